// Round 1
// 513.198 us; speedup vs baseline: 1.0900x; 1.0900x over previous
//
#include <hip/hip_runtime.h>
#include <hip/hip_bf16.h>
#include <math.h>

// VideoSwinBasicLayer: 2 swin blocks (W-MSA, SW-MSA) on (1,16,56,56,128), NH=4,
// window (8,7,7) -> L=392, nW=128, shift (4,3,3), HID=512. IO f32.
// R8: attn occupancy 2x (512 thr / 8 waves, LDS 61440B via XOR-swizzled K[416][32]
// + V_T stride 416), exp2-domain softmax (log2e folded into q-scale & bias table),
// defer-max rescale (THR=8), vectorized V_T staging loads.
// ws: buf1 12.85MB | bufq 38.5MB | wtsT 0.79MB | bm 10.44MB = 62.6MB.

#define NTOK 50176   // 16*56*56
#define CC   128
#define LL   392
#define NWIN 128
#define NHEAD 4
#define HDIM 32
#define QKSCALE 0.17677669529663687f  // 32^-0.5
#define LOG2E   1.4426950408889634f

// attention LDS layout (u16 units)
#define KOFF    0             // K: 416 rows x 32, XOR granule swizzle = 13312 u16
#define VSTRIDE 416
#define VOFF    13312         // V_T: 32 x 416 = 13312 u16
#define POFF    26624         // P: 8 waves x 512 = 4096 u16 (XOR-swizzled blocks)
#define LDS_U16 30720         // 61440 B

// K tile addressing: row-major [row][32] with b128-granule g (0..3) swizzled by
// row&3 -> conflict-free ds_read_b128 / ds_write_b128 without padding.
#define KADDR(row, g) ((((row) << 5)) + ((((g) ^ ((row) & 3))) << 3))

#define BM_PER_HEAD (13*16*392)            // u32 per (cls,head) slice
#define BM_TOTAL    (8*4*BM_PER_HEAD)      // 10.44 MB

typedef unsigned short u16;
typedef unsigned int   u32;
typedef unsigned long long u64;
typedef __attribute__((ext_vector_type(8))) short short8;
typedef __attribute__((ext_vector_type(4))) float f32x4;

// async global->LDS, 16B per lane; LDS dest = wave-uniform base + lane*16.
#define GLDS(gp, lp) __builtin_amdgcn_global_load_lds( \
    (const __attribute__((address_space(1))) void*)(gp), \
    (__attribute__((address_space(3))) void*)(lp), 16, 0, 0)

__device__ __forceinline__ float b2f_lo(u32 u){ return __uint_as_float(u<<16); }
__device__ __forceinline__ float b2f_hi(u32 u){ return __uint_as_float(u & 0xffff0000u); }
__device__ __forceinline__ u16 f2b(float f){
  __hip_bfloat16 h = __float2bfloat16(f);
  return *reinterpret_cast<u16*>(&h);
}

// window-ordered row r -> flat token position (roll(+shift) both directions).
__device__ __forceinline__ int row_to_pos(int r, int shifted){
  int w = r / LL, t = r - w*LL;
  int wd = w >> 6, wh = (w >> 3) & 7, ww = w & 7;
  int td = t / 49, rem = t - td*49, th = rem / 7, tw = rem - th*7;
  int d = wd*8 + td, h = wh*7 + th, x = ww*7 + tw;
  if (shifted){ d = (d+4)&15; h += 3; if (h>=56) h-=56; x += 3; if (x>=56) x-=56; }
  return (d*56 + h)*56 + x;
}

// LayerNorm over C=128 (f32 src), bf16 out. One wave per row.
__global__ __launch_bounds__(256) void ln_kernel(
    const float* __restrict__ xf, const float* __restrict__ g,
    const float* __restrict__ b, u16* __restrict__ out, int do_map, int shifted)
{
  int wave = threadIdx.x >> 6, lane = threadIdx.x & 63;
  int r = blockIdx.x*4 + wave;
  int pos = do_map ? row_to_pos(r, shifted) : r;
  long src = (long)pos * CC;
  float v0 = xf[src+lane], v1 = xf[src+64+lane];
  float s = v0+v1, ss = v0*v0 + v1*v1;
  #pragma unroll
  for (int o=32; o>0; o>>=1){ s += __shfl_xor(s,o); ss += __shfl_xor(ss,o); }
  float mean = s*(1.f/CC);
  float var  = ss*(1.f/CC) - mean*mean;
  float rstd = rsqrtf(var + 1e-5f);
  long dst = (long)r*CC;
  out[dst + lane]      = f2b((v0-mean)*rstd*g[lane]    + b[lane]);
  out[dst + 64 + lane] = f2b((v1-mean)*rstd*g[64+lane] + b[64+lane]);
}

// Transpose+convert weights: in f32 [Kd][Nd] row-major -> out bf16 [Nd][Kd].
__global__ __launch_bounds__(256) void wt_kernel(
    const float* __restrict__ in, u16* __restrict__ out, int Kd, int Nd, int total)
{
  int t = blockIdx.x*256 + threadIdx.x;
  if (t >= total) return;
  int n = t / Kd, k = t - n*Kd;
  out[t] = f2b(in[k*Nd + n]);
}

// Packed bias(+mask) table in exp2 domain: bm[cls][h][s][jj][i] u32 =
// (bf16 v(j=s*32+jj, i), bf16 v(j+16, i)).
// v = (rpb-bias - 100*maskneq(cls)) * log2e;  j>=392 -> -1e30.
__global__ __launch_bounds__(256) void biasm_kernel(
    const float* __restrict__ rpb, u32* __restrict__ bm)
{
  int t = blockIdx.x*256 + threadIdx.x;
  if (t >= BM_TOTAL) return;
  int i = t % 392; int rest = t / 392;
  int jj = rest % 16; rest /= 16;
  int s  = rest % 13; rest /= 13;
  int h  = rest % 4;  int cls = rest / 4;
  int tdi=i/49, rmi=i-tdi*49, thi=rmi/7, twi=rmi-thi*7;
  u32 pack = 0;
  #pragma unroll
  for (int half=0; half<2; half++){
    int j = s*32 + jj + half*16;
    float v = -1e30f;
    if (j < LL){
      int tdj=j/49, rmj=j-tdj*49, thj=rmj/7, twj=rmj-thj*7;
      int idx = (tdi-tdj)*169 + (thi-thj)*13 + (twi-twj) + 1267;
      v = rpb[idx*NHEAD + h];
      bool neq = ((cls&4) && ((tdi<4) != (tdj<4)))
              || ((cls&2) && ((thi<4) != (thj<4)))
              || ((cls&1) && ((twi<4) != (twj<4)));
      if (neq) v -= 100.f;
      v *= LOG2E;
    }
    pack |= ((u32)f2b(v)) << (16*half);
  }
  bm[t] = pack;
}

// MFMA GEMM, m97-style staging: C[128x128] = A[rows x KD](bf16) @ Wt^T (Wt [N][K]
// bf16). Unpadded LDS [128][32]; global_load_lds width 16 (4 issues/wave/K-iter).
// EPI: 0 = (+bias)*scale -> bf16 (qkv; scale only blockIdx.y==0)
//      1 = +bias, GELU -> bf16 | 2 = +bias, scatter, +Res -> f32 | 3 = accum f32
template<int KD, int EPI>
__global__ __launch_bounds__(256) void mm_kernel(
    const u16* __restrict__ A, const u16* __restrict__ Wt, int ldw,
    const float* __restrict__ bias, u16* __restrict__ OutB, int ldo,
    float* __restrict__ OutF, const float* __restrict__ Res,
    float scaleq, int shifted, int use_bias)
{
  __shared__ __align__(16) u16 As[128*32];
  __shared__ __align__(16) u16 Bs[128*32];
  const int tid = threadIdx.x, lane = tid & 63, wv = tid >> 6;
  const int quad = lane >> 4, l15 = lane & 15;
  const int rh = wv >> 1, ch = wv & 1;
  const int r0 = blockIdx.x * 128, n0 = blockIdx.y * 128;
  const int srow = lane >> 2, spart = (lane & 3) * 8;  // staging: 16 rows/issue

  f32x4 acc[4][4] = {};

  for (int kt = 0; kt < KD/32; kt++){
    const int k0 = kt*32;
    #pragma unroll
    for (int t=0;t<2;t++){
      const int rowbase = wv*32 + t*16;
      GLDS(&A [(long)(r0 + rowbase + srow)*KD  + k0 + spart], &As[rowbase*32]);
      GLDS(&Wt[(long)(n0 + rowbase + srow)*ldw + k0 + spart], &Bs[rowbase*32]);
    }
    __syncthreads();
    short8 af[4], bf[4];
    #pragma unroll
    for (int rt=0;rt<4;rt++)
      af[rt] = *reinterpret_cast<const short8*>(&As[(rh*64 + rt*16 + l15)*32 + quad*8]);
    #pragma unroll
    for (int ct=0;ct<4;ct++)
      bf[ct] = *reinterpret_cast<const short8*>(&Bs[(ch*64 + ct*16 + l15)*32 + quad*8]);
    #pragma unroll
    for (int rt=0;rt<4;rt++)
      #pragma unroll
      for (int ct=0;ct<4;ct++)
        acc[rt][ct] = __builtin_amdgcn_mfma_f32_16x16x32_bf16(af[rt], bf[ct], acc[rt][ct], 0,0,0);
    __syncthreads();
  }

  #pragma unroll
  for (int rt=0;rt<4;rt++){
    #pragma unroll
    for (int rr=0;rr<4;rr++){
      const int row_g = r0 + rh*64 + rt*16 + quad*4 + rr;
      long pos = 0;
      if (EPI == 2) pos = (long)row_to_pos(row_g, shifted) * CC;
      #pragma unroll
      for (int ct=0;ct<4;ct++){
        const int col_g = n0 + ch*64 + ct*16 + l15;
        float v = acc[rt][ct][rr];
        if (EPI == 0){
          float sc = (blockIdx.y == 0) ? scaleq : 1.f;
          v = (v + bias[col_g]) * sc;
          OutB[(long)row_g*ldo + col_g] = f2b(v);
        } else if (EPI == 1){
          v += bias[col_g];
          v = 0.5f*v*(1.f + erff(v*0.70710678118654752f));
          OutB[(long)row_g*ldo + col_g] = f2b(v);
        } else if (EPI == 2){
          OutF[pos + col_g] = Res[pos + col_g] + v + bias[col_g];
        } else {
          float o = OutF[(long)row_g*CC + col_g] + v;
          if (use_bias) o += bias[col_g];
          OutF[(long)row_g*CC + col_g] = o;
        }
      }
    }
  }
}

// MFMA flash attention, S^T orientation. One block per (window, head); 8 waves
// x 16-row q-tiles (qt += 8). Scalar softmax state in exp2 domain (q-row =
// lane&15), defer-max rescale (THR=8). Packed bias+mask prefetched one step
// ahead (with next K-frags). P round-trip through XOR-swizzled wave-private
// LDS (conflict-free b64 writes / b128 read). K tile: [416][32] with per-row
// XOR granule swizzle (conflict-free, no pad). V_T stride 416.
__global__ __launch_bounds__(512, 4) void attn_kernel(
    const u16* __restrict__ qkv, const u32* __restrict__ bm,
    u16* __restrict__ out, int shifted)
{
  __shared__ __align__(16) u16 lds[LDS_U16];

  const int w = blockIdx.x >> 2, head = blockIdx.x & 3;
  const int tid = threadIdx.x, lane = tid & 63, wave = tid >> 6;
  const int quad = lane >> 4, l15 = lane & 15;
  const long qkvbase = (long)w * LL * 384;
  const int wd = w>>6, wh = (w>>3)&7, ww = w&7;
  const int cls = shifted ? (((wd!=0)?4:0) | ((wh==7)?2:0) | ((ww==7)?1:0)) : 0;
  const u32* __restrict__ bmh = bm + (size_t)(cls*NHEAD + head)*BM_PER_HEAD;
  const int pbase = POFF + wave*512;
  const int pwb0 = ((quad>>1)     ^ (l15&3))*8 + (quad&1)*4;  // w0 phys offset
  const int pwb1 = ((2+(quad>>1)) ^ (l15&3))*8 + (quad&1)*4;  // w1 phys offset

  // stage K (rows 392..415 zeroed), XOR granule swizzle
  for (int idx = tid; idx < 416*4; idx += 512){
    int key = idx >> 2, part = idx & 3;
    short8 val = {0,0,0,0,0,0,0,0};
    if (key < LL)
      val = *reinterpret_cast<const short8*>(&qkv[qkvbase + (long)key*384 + 128 + head*HDIM + part*8]);
    *reinterpret_cast<short8*>(&lds[KOFF + KADDR(key, part)]) = val;
  }
  // stage V transposed (keys 392..415 zeroed); vectorized global loads
  for (int idx = tid; idx < 416*4; idx += 512){
    int key = idx >> 2, part = (idx & 3) * 8;
    short8 val = {0,0,0,0,0,0,0,0};
    if (key < LL)
      val = *reinterpret_cast<const short8*>(&qkv[qkvbase + (long)key*384 + 256 + head*HDIM + part]);
    #pragma unroll
    for (int j=0;j<8;j++)
      lds[VOFF + (part+j)*VSTRIDE + key] = ((const u16*)&val)[j];
  }
  __syncthreads();

  for (int qt = wave; qt < 25; qt += 8){
    int iq = qt*16 + l15; if (iq > LL-1) iq = LL-1;
    short8 qf = *reinterpret_cast<const short8*>(&qkv[qkvbase + (long)iq*384 + head*HDIM + quad*8]);

    float m_s = -1e30f, l_s = 0.f;
    f32x4 oc0 = {0.f,0.f,0.f,0.f}, oc1 = {0.f,0.f,0.f,0.f};

    // prefetch step 0
    u32 bmv[4];
    {
      const u32* bp = &bmh[iq];
      #pragma unroll
      for (int r=0;r<4;r++) bmv[r] = bp[(quad*4+r)*392];
    }
    short8 kf0 = *reinterpret_cast<const short8*>(&lds[KOFF + KADDR(l15, quad)]);
    short8 kf1 = *reinterpret_cast<const short8*>(&lds[KOFF + KADDR(16 + l15, quad)]);

    for (int s = 0; s < 13; s++){
      const int kbase = s*32;
      // prefetch next step's bias+mask (global) and K-frags (LDS)
      u32 bmn[4] = {};
      short8 kn0 = {}, kn1 = {};
      if (s < 12){
        const u32* bp = &bmh[(size_t)((s+1)*16)*392 + iq];
        #pragma unroll
        for (int r=0;r<4;r++) bmn[r] = bp[(quad*4+r)*392];
        kn0 = *reinterpret_cast<const short8*>(&lds[KOFF + KADDR(kbase + 32 + l15, quad)]);
        kn1 = *reinterpret_cast<const short8*>(&lds[KOFF + KADDR(kbase + 48 + l15, quad)]);
      }

      f32x4 z = {0.f,0.f,0.f,0.f};
      f32x4 c0 = __builtin_amdgcn_mfma_f32_16x16x32_bf16(kf0, qf, z, 0,0,0);
      f32x4 c1 = __builtin_amdgcn_mfma_f32_16x16x32_bf16(kf1, qf, z, 0,0,0);
      // c0[r]: S[qrow=iq][key=kbase+quad*4+r]; c1[r]: key +16  (log2 domain)

      float s0[4], s1[4];
      float mt = -1e30f;
      #pragma unroll
      for (int r=0;r<4;r++){
        s0[r] = c0[r] + b2f_lo(bmv[r]);
        s1[r] = c1[r] + b2f_hi(bmv[r]);
        mt = fmaxf(mt, fmaxf(s0[r], s1[r]));
      }
      mt = fmaxf(mt, __shfl_xor(mt, 16));
      mt = fmaxf(mt, __shfl_xor(mt, 32));

      // defer-max: only rescale when the running max grows by > 8 (p <= 2^8)
      if (!__all(mt <= m_s + 8.f)){
        float mn = fmaxf(m_s, mt);
        float al = exp2f(m_s - mn);
        m_s = mn;
        l_s *= al;
        #pragma unroll
        for (int r=0;r<4;r++){
          float alr = __shfl(al, quad*4 + r);
          oc0[r] *= alr; oc1[r] *= alr;
        }
      }

      float rs = 0.f;
      u16 pb0[4], pb1[4];
      #pragma unroll
      for (int r=0;r<4;r++){
        float p0 = exp2f(s0[r] - m_s);
        float p1 = exp2f(s1[r] - m_s);
        rs += p0 + p1;
        pb0[r] = f2b(p0); pb1[r] = f2b(p1);
      }
      rs += __shfl_xor(rs, 16);
      rs += __shfl_xor(rs, 32);
      l_s += rs;

      // P -> wave-private LDS (XOR-swizzled 8-u16 blocks, conflict-free)
      u64 w0 = (u64)pb0[0] | ((u64)pb0[1]<<16) | ((u64)pb0[2]<<32) | ((u64)pb0[3]<<48);
      u64 w1 = (u64)pb1[0] | ((u64)pb1[1]<<16) | ((u64)pb1[2]<<32) | ((u64)pb1[3]<<48);
      *reinterpret_cast<u64*>(&lds[pbase + l15*32 + pwb0]) = w0;
      *reinterpret_cast<u64*>(&lds[pbase + l15*32 + pwb1]) = w1;

      short8 pa  = *reinterpret_cast<const short8*>(&lds[pbase + l15*32 + ((quad^(l15&3))*8)]);
      short8 vb0 = *reinterpret_cast<const short8*>(&lds[VOFF + l15*VSTRIDE + kbase + quad*8]);
      short8 vb1 = *reinterpret_cast<const short8*>(&lds[VOFF + (16+l15)*VSTRIDE + kbase + quad*8]);
      oc0 = __builtin_amdgcn_mfma_f32_16x16x32_bf16(pa, vb0, oc0, 0,0,0);
      oc1 = __builtin_amdgcn_mfma_f32_16x16x32_bf16(pa, vb1, oc1, 0,0,0);

      #pragma unroll
      for (int r=0;r<4;r++) bmv[r] = bmn[r];
      kf0 = kn0; kf1 = kn1;
    }

    float inv = 1.f / l_s;
    #pragma unroll
    for (int r=0;r<4;r++){
      float invr = __shfl(inv, quad*4 + r);
      int i = qt*16 + quad*4 + r;
      if (i < LL){
        long o = ((long)(w*LL + i))*CC + head*HDIM;
        out[o + l15]      = f2b(oc0[r]*invr);
        out[o + 16 + l15] = f2b(oc1[r]*invr);
      }
    }
  }
}

extern "C" void kernel_launch(void* const* d_in, const int* in_sizes, int n_in,
                              void* d_out, int out_size, void* d_ws, size_t ws_size,
                              hipStream_t stream)
{
  const float* x     = (const float*)d_in[0];
  const float* ln1g  = (const float*)d_in[1];
  const float* ln1b  = (const float*)d_in[2];
  const float* qkvw  = (const float*)d_in[3];
  const float* qkvb  = (const float*)d_in[4];
  const float* rpb   = (const float*)d_in[5];
  const float* projw = (const float*)d_in[6];
  const float* projb = (const float*)d_in[7];
  const float* ln2g  = (const float*)d_in[8];
  const float* ln2b  = (const float*)d_in[9];
  const float* fc1w  = (const float*)d_in[10];
  const float* fc1b  = (const float*)d_in[11];
  const float* fc2w  = (const float*)d_in[12];
  const float* fc2b  = (const float*)d_in[13];
  float* outf = (float*)d_out;                  // f32 residual stream / output

  u16* buf1 = (u16*)d_ws;                       // bf16 act, NTOK*128
  u16* bufq = buf1 + (size_t)NTOK*CC;           // bf16 qkv / mlp hidden half
  u16* wts  = bufq + (size_t)NTOK*384;          // transposed bf16 weights
  u32* bm   = (u32*)(wts + 393216);             // packed bias+mask table

  for (int blk = 0; blk < 2; ++blk){
    u16* wb = wts + (size_t)blk*196608;
    wt_kernel<<<(49152+255)/256, 256, 0, stream>>>(qkvw + (size_t)blk*128*384, wb,          128, 384, 49152);
    wt_kernel<<<(16384+255)/256, 256, 0, stream>>>(projw + (size_t)blk*128*128, wb+49152,   128, 128, 16384);
    wt_kernel<<<(65536+255)/256, 256, 0, stream>>>(fc1w  + (size_t)blk*128*512, wb+65536,   128, 512, 65536);
    wt_kernel<<<(65536+255)/256, 256, 0, stream>>>(fc2w  + (size_t)blk*512*128, wb+131072,  512, 128, 65536);
  }

  for (int blk = 0; blk < 2; ++blk){
    const int sh = blk;
    const float* resid = (blk==0) ? x : outf;
    u16* wb = wts + (size_t)blk*196608;

    biasm_kernel<<<(BM_TOTAL+255)/256, 256, 0, stream>>>(
        rpb + (size_t)blk*2535*NHEAD, bm);
    // LN1 + roll + window-partition gather
    ln_kernel<<<NTOK/4, 256, 0, stream>>>(resid,
        ln1g + blk*CC, ln1b + blk*CC, buf1, 1, sh);
    // QKV GEMM (q pre-scaled by 32^-0.5 * log2e for exp2-domain softmax)
    mm_kernel<128,0><<<dim3(392,3), 256, 0, stream>>>(
        buf1, wb, 128, qkvb + blk*384, bufq, 384,
        nullptr, nullptr, QKSCALE*LOG2E, 0, 0);
    // attention (128 windows x 4 heads), 8 waves/block
    attn_kernel<<<NWIN*NHEAD, 512, 0, stream>>>(bufq, bm, buf1, sh);
    // proj + reverse/roll-back scatter + residual -> outf
    mm_kernel<128,2><<<dim3(392,1), 256, 0, stream>>>(
        buf1, wb+49152, 128, projb + blk*CC, nullptr, 0,
        outf, resid, 1.f, sh, 0);
    // LN2
    ln_kernel<<<NTOK/4, 256, 0, stream>>>(outf,
        ln2g + blk*CC, ln2b + blk*CC, buf1, 0, 0);
    // MLP in 2 column-halves of 256 (hidden half reuses bufq)
    for (int h = 0; h < 2; ++h){
      mm_kernel<128,1><<<dim3(392,2), 256, 0, stream>>>(
          buf1, wb + 65536 + (size_t)h*256*128, 128,
          fc1b + blk*512 + h*256, bufq, 256,
          nullptr, nullptr, 1.f, 0, 0);
      mm_kernel<256,3><<<dim3(392,1), 256, 0, stream>>>(
          bufq, wb + 131072 + h*256, 512,
          fc2b + blk*CC, nullptr, 0,
          outf, nullptr, 1.f, 0, h==0 ? 1 : 0);
    }
  }
}

// Round 2
// 505.178 us; speedup vs baseline: 1.1073x; 1.0159x over previous
//
#include <hip/hip_runtime.h>
#include <hip/hip_bf16.h>
#include <math.h>

// VideoSwinBasicLayer: 2 swin blocks (W-MSA, SW-MSA) on (1,16,56,56,128), NH=4,
// window (8,7,7) -> L=392, nW=128, shift (4,3,3), HID=512. IO f32.
// R9: attn 64-key softmax steps (joint max/sum/P-roundtrip per 64 keys),
// V tile stride 448 + row-XOR granule swizzle (conflict-free b128 reads),
// setprio around MFMA clusters, biasm builds only cls=0 for block 0.
// ws: buf1 12.85MB | bufq 38.5MB | wtsT 0.79MB | bm 10.44MB = 62.6MB.

#define NTOK 50176   // 16*56*56
#define CC   128
#define LL   392
#define NWIN 128
#define NHEAD 4
#define HDIM 32
#define QKSCALE 0.17677669529663687f  // 32^-0.5
#define LOG2E   1.4426950408889634f

// attention LDS layout (u16 units)
#define KOFF    0             // K: 416 rows x 32, XOR granule swizzle = 13312 u16
#define VOFF    13312         // V_T: 32 x 448 (XOR granule swizzle) = 14336 u16
#define POFF    27648         // P: 8 waves x 1024 (16 q-rows x 128B, swizzled)
#define LDS_U16 35840         // 71680 B -> 2 blocks/CU

// K tile: row-major [row][32] with b128-granule g (0..3) swizzled by row&3.
#define KADDR(row, g) ((((row) << 5)) + ((((g) ^ ((row) & 3))) << 3))
// V tile: [d][448] u16, 16B granule (key>>3) swizzled by d&7. k must be %8==0 here.
#define VADDR(d, k) (VOFF + (d)*448 + (((((k) >> 3)) ^ ((d) & 7)) << 3))

#define BM_PER_HEAD (13*16*392)            // u32 per (cls,head) slice
#define BM_TOTAL    (8*4*BM_PER_HEAD)      // 10.44 MB

typedef unsigned short u16;
typedef unsigned int   u32;
typedef unsigned long long u64;
typedef __attribute__((ext_vector_type(8))) short short8;
typedef __attribute__((ext_vector_type(4))) float f32x4;

// async global->LDS, 16B per lane; LDS dest = wave-uniform base + lane*16.
#define GLDS(gp, lp) __builtin_amdgcn_global_load_lds( \
    (const __attribute__((address_space(1))) void*)(gp), \
    (__attribute__((address_space(3))) void*)(lp), 16, 0, 0)

__device__ __forceinline__ float b2f_lo(u32 u){ return __uint_as_float(u<<16); }
__device__ __forceinline__ float b2f_hi(u32 u){ return __uint_as_float(u & 0xffff0000u); }
__device__ __forceinline__ u16 f2b(float f){
  __hip_bfloat16 h = __float2bfloat16(f);
  return *reinterpret_cast<u16*>(&h);
}

// window-ordered row r -> flat token position (roll(+shift) both directions).
__device__ __forceinline__ int row_to_pos(int r, int shifted){
  int w = r / LL, t = r - w*LL;
  int wd = w >> 6, wh = (w >> 3) & 7, ww = w & 7;
  int td = t / 49, rem = t - td*49, th = rem / 7, tw = rem - th*7;
  int d = wd*8 + td, h = wh*7 + th, x = ww*7 + tw;
  if (shifted){ d = (d+4)&15; h += 3; if (h>=56) h-=56; x += 3; if (x>=56) x-=56; }
  return (d*56 + h)*56 + x;
}

// LayerNorm over C=128 (f32 src), bf16 out. One wave per row.
__global__ __launch_bounds__(256) void ln_kernel(
    const float* __restrict__ xf, const float* __restrict__ g,
    const float* __restrict__ b, u16* __restrict__ out, int do_map, int shifted)
{
  int wave = threadIdx.x >> 6, lane = threadIdx.x & 63;
  int r = blockIdx.x*4 + wave;
  int pos = do_map ? row_to_pos(r, shifted) : r;
  long src = (long)pos * CC;
  float v0 = xf[src+lane], v1 = xf[src+64+lane];
  float s = v0+v1, ss = v0*v0 + v1*v1;
  #pragma unroll
  for (int o=32; o>0; o>>=1){ s += __shfl_xor(s,o); ss += __shfl_xor(ss,o); }
  float mean = s*(1.f/CC);
  float var  = ss*(1.f/CC) - mean*mean;
  float rstd = rsqrtf(var + 1e-5f);
  long dst = (long)r*CC;
  out[dst + lane]      = f2b((v0-mean)*rstd*g[lane]    + b[lane]);
  out[dst + 64 + lane] = f2b((v1-mean)*rstd*g[64+lane] + b[64+lane]);
}

// Transpose+convert weights: in f32 [Kd][Nd] row-major -> out bf16 [Nd][Kd].
__global__ __launch_bounds__(256) void wt_kernel(
    const float* __restrict__ in, u16* __restrict__ out, int Kd, int Nd, int total)
{
  int t = blockIdx.x*256 + threadIdx.x;
  if (t >= total) return;
  int n = t / Kd, k = t - n*Kd;
  out[t] = f2b(in[k*Nd + n]);
}

// Packed bias(+mask) table in exp2 domain: bm[cls][h][s][jj][i] u32 =
// (bf16 v(j=s*32+jj, i), bf16 v(j+16, i)).
// v = (rpb-bias - 100*maskneq(cls)) * log2e;  j>=392 -> -1e30.
// total = ncls*4*BM_PER_HEAD (block 0 only needs cls=0).
__global__ __launch_bounds__(256) void biasm_kernel(
    const float* __restrict__ rpb, u32* __restrict__ bm, int total)
{
  int t = blockIdx.x*256 + threadIdx.x;
  if (t >= total) return;
  int i = t % 392; int rest = t / 392;
  int jj = rest % 16; rest /= 16;
  int s  = rest % 13; rest /= 13;
  int h  = rest % 4;  int cls = rest / 4;
  int tdi=i/49, rmi=i-tdi*49, thi=rmi/7, twi=rmi-thi*7;
  u32 pack = 0;
  #pragma unroll
  for (int half=0; half<2; half++){
    int j = s*32 + jj + half*16;
    float v = -1e30f;
    if (j < LL){
      int tdj=j/49, rmj=j-tdj*49, thj=rmj/7, twj=rmj-thj*7;
      int idx = (tdi-tdj)*169 + (thi-thj)*13 + (twi-twj) + 1267;
      v = rpb[idx*NHEAD + h];
      bool neq = ((cls&4) && ((tdi<4) != (tdj<4)))
              || ((cls&2) && ((thi<4) != (thj<4)))
              || ((cls&1) && ((twi<4) != (twj<4)));
      if (neq) v -= 100.f;
      v *= LOG2E;
    }
    pack |= ((u32)f2b(v)) << (16*half);
  }
  bm[t] = pack;
}

// MFMA GEMM, m97-style staging: C[128x128] = A[rows x KD](bf16) @ Wt^T (Wt [N][K]
// bf16). Unpadded LDS [128][32]; global_load_lds width 16 (4 issues/wave/K-iter).
// EPI: 0 = (+bias)*scale -> bf16 (qkv; scale only blockIdx.y==0)
//      1 = +bias, GELU -> bf16 | 2 = +bias, scatter, +Res -> f32 | 3 = accum f32
template<int KD, int EPI>
__global__ __launch_bounds__(256) void mm_kernel(
    const u16* __restrict__ A, const u16* __restrict__ Wt, int ldw,
    const float* __restrict__ bias, u16* __restrict__ OutB, int ldo,
    float* __restrict__ OutF, const float* __restrict__ Res,
    float scaleq, int shifted, int use_bias)
{
  __shared__ __align__(16) u16 As[128*32];
  __shared__ __align__(16) u16 Bs[128*32];
  const int tid = threadIdx.x, lane = tid & 63, wv = tid >> 6;
  const int quad = lane >> 4, l15 = lane & 15;
  const int rh = wv >> 1, ch = wv & 1;
  const int r0 = blockIdx.x * 128, n0 = blockIdx.y * 128;
  const int srow = lane >> 2, spart = (lane & 3) * 8;  // staging: 16 rows/issue

  f32x4 acc[4][4] = {};

  for (int kt = 0; kt < KD/32; kt++){
    const int k0 = kt*32;
    #pragma unroll
    for (int t=0;t<2;t++){
      const int rowbase = wv*32 + t*16;
      GLDS(&A [(long)(r0 + rowbase + srow)*KD  + k0 + spart], &As[rowbase*32]);
      GLDS(&Wt[(long)(n0 + rowbase + srow)*ldw + k0 + spart], &Bs[rowbase*32]);
    }
    __syncthreads();
    short8 af[4], bf[4];
    #pragma unroll
    for (int rt=0;rt<4;rt++)
      af[rt] = *reinterpret_cast<const short8*>(&As[(rh*64 + rt*16 + l15)*32 + quad*8]);
    #pragma unroll
    for (int ct=0;ct<4;ct++)
      bf[ct] = *reinterpret_cast<const short8*>(&Bs[(ch*64 + ct*16 + l15)*32 + quad*8]);
    #pragma unroll
    for (int rt=0;rt<4;rt++)
      #pragma unroll
      for (int ct=0;ct<4;ct++)
        acc[rt][ct] = __builtin_amdgcn_mfma_f32_16x16x32_bf16(af[rt], bf[ct], acc[rt][ct], 0,0,0);
    __syncthreads();
  }

  #pragma unroll
  for (int rt=0;rt<4;rt++){
    #pragma unroll
    for (int rr=0;rr<4;rr++){
      const int row_g = r0 + rh*64 + rt*16 + quad*4 + rr;
      long pos = 0;
      if (EPI == 2) pos = (long)row_to_pos(row_g, shifted) * CC;
      #pragma unroll
      for (int ct=0;ct<4;ct++){
        const int col_g = n0 + ch*64 + ct*16 + l15;
        float v = acc[rt][ct][rr];
        if (EPI == 0){
          float sc = (blockIdx.y == 0) ? scaleq : 1.f;
          v = (v + bias[col_g]) * sc;
          OutB[(long)row_g*ldo + col_g] = f2b(v);
        } else if (EPI == 1){
          v += bias[col_g];
          v = 0.5f*v*(1.f + erff(v*0.70710678118654752f));
          OutB[(long)row_g*ldo + col_g] = f2b(v);
        } else if (EPI == 2){
          OutF[pos + col_g] = Res[pos + col_g] + v + bias[col_g];
        } else {
          float o = OutF[(long)row_g*CC + col_g] + v;
          if (use_bias) o += bias[col_g];
          OutF[(long)row_g*CC + col_g] = o;
        }
      }
    }
  }
}

// MFMA flash attention, S^T orientation. One block per (window, head); 8 waves
// x 16-row q-tiles (qt += 8). 64-key softmax steps: joint max/exp/sum and a
// single P LDS round-trip per 64 keys (halves the serial chain per key).
// Scalar softmax state in exp2 domain (q-row = lane&15), defer-max (THR=8).
// P region per wave: 16 rows x 128B, granule-XOR swizzle (conflict-free).
__global__ __launch_bounds__(512, 4) void attn_kernel(
    const u16* __restrict__ qkv, const u32* __restrict__ bm,
    u16* __restrict__ out, int shifted)
{
  __shared__ __align__(16) u16 lds[LDS_U16];

  const int w = blockIdx.x >> 2, head = blockIdx.x & 3;
  const int tid = threadIdx.x, lane = tid & 63, wave = tid >> 6;
  const int quad = lane >> 4, l15 = lane & 15;
  const long qkvbase = (long)w * LL * 384;
  const int wd = w>>6, wh = (w>>3)&7, ww = w&7;
  const int cls = shifted ? (((wd!=0)?4:0) | ((wh==7)?2:0) | ((ww==7)?1:0)) : 0;
  const u32* __restrict__ bmh = bm + (size_t)(cls*NHEAD + head)*BM_PER_HEAD;
  const int pbase = POFF + wave*1024;
  const int swz = l15 & 7;
  const int prow = pbase + l15*64;
  const int q2 = quad >> 1, qh = (quad & 1) << 2;

  // stage K (rows 392..415 zeroed), XOR granule swizzle
  for (int idx = tid; idx < 416*4; idx += 512){
    int key = idx >> 2, part = idx & 3;
    short8 val = {0,0,0,0,0,0,0,0};
    if (key < LL)
      val = *reinterpret_cast<const short8*>(&qkv[qkvbase + (long)key*384 + 128 + head*HDIM + part*8]);
    *reinterpret_cast<short8*>(&lds[KOFF + KADDR(key, part)]) = val;
  }
  // stage V transposed (keys 392..415 zeroed), granule swizzled by d&7
  for (int idx = tid; idx < 416*4; idx += 512){
    int key = idx >> 2, dbase = (idx & 3) * 8;
    short8 val = {0,0,0,0,0,0,0,0};
    if (key < LL)
      val = *reinterpret_cast<const short8*>(&qkv[qkvbase + (long)key*384 + 256 + head*HDIM + dbase]);
    #pragma unroll
    for (int j=0;j<8;j++){
      int d = dbase + j;
      lds[VOFF + d*448 + ((((key>>3) ^ (d&7))) << 3) + (key & 7)] = ((const u16*)&val)[j];
    }
  }
  __syncthreads();

  for (int qt = wave; qt < 25; qt += 8){
    int iq = qt*16 + l15; if (iq > LL-1) iq = LL-1;
    short8 qf = *reinterpret_cast<const short8*>(&qkv[qkvbase + (long)iq*384 + head*HDIM + quad*8]);

    float m_s = -1e30f, l_s = 0.f;
    f32x4 oc0 = {0.f,0.f,0.f,0.f}, oc1 = {0.f,0.f,0.f,0.f};

    // prefetch it=0: 4 K-frags + 2 bm chunks
    u32 bmA[4], bmB[4];
    {
      const u32* bp = &bmh[iq];
      #pragma unroll
      for (int r=0;r<4;r++) bmA[r] = bp[(      quad*4 + r)*392];
      #pragma unroll
      for (int r=0;r<4;r++) bmB[r] = bp[(16 + quad*4 + r)*392];
    }
    short8 kf0 = *reinterpret_cast<const short8*>(&lds[KOFF + KADDR(     l15, quad)]);
    short8 kf1 = *reinterpret_cast<const short8*>(&lds[KOFF + KADDR(16 + l15, quad)]);
    short8 kf2 = *reinterpret_cast<const short8*>(&lds[KOFF + KADDR(32 + l15, quad)]);
    short8 kf3 = *reinterpret_cast<const short8*>(&lds[KOFF + KADDR(48 + l15, quad)]);

    for (int it = 0; it < 6; it++){
      const int kb = it*64;
      // prefetch next 64-key group (or the 32-key tail when it==5)
      u32 bmAn[4] = {}, bmBn[4] = {};
      short8 kn0 = {}, kn1 = {}, kn2 = {}, kn3 = {};
      if (it < 5){
        const u32* bp = &bmh[(size_t)((2*it+2)*16)*392 + iq];
        #pragma unroll
        for (int r=0;r<4;r++) bmAn[r] = bp[(      quad*4 + r)*392];
        #pragma unroll
        for (int r=0;r<4;r++) bmBn[r] = bp[(16 + quad*4 + r)*392];
        kn0 = *reinterpret_cast<const short8*>(&lds[KOFF + KADDR(kb + 64 + l15, quad)]);
        kn1 = *reinterpret_cast<const short8*>(&lds[KOFF + KADDR(kb + 80 + l15, quad)]);
        kn2 = *reinterpret_cast<const short8*>(&lds[KOFF + KADDR(kb + 96 + l15, quad)]);
        kn3 = *reinterpret_cast<const short8*>(&lds[KOFF + KADDR(kb +112 + l15, quad)]);
      } else {
        const u32* bp = &bmh[(size_t)(12*16)*392 + iq];
        #pragma unroll
        for (int r=0;r<4;r++) bmAn[r] = bp[(quad*4 + r)*392];
        kn0 = *reinterpret_cast<const short8*>(&lds[KOFF + KADDR(384 + l15, quad)]);
        kn1 = *reinterpret_cast<const short8*>(&lds[KOFF + KADDR(400 + l15, quad)]);
      }

      f32x4 z = {0.f,0.f,0.f,0.f};
      __builtin_amdgcn_s_setprio(1);
      f32x4 c0 = __builtin_amdgcn_mfma_f32_16x16x32_bf16(kf0, qf, z, 0,0,0);
      f32x4 c1 = __builtin_amdgcn_mfma_f32_16x16x32_bf16(kf1, qf, z, 0,0,0);
      f32x4 c2 = __builtin_amdgcn_mfma_f32_16x16x32_bf16(kf2, qf, z, 0,0,0);
      f32x4 c3 = __builtin_amdgcn_mfma_f32_16x16x32_bf16(kf3, qf, z, 0,0,0);
      __builtin_amdgcn_s_setprio(0);
      // c0[r]: S[key=kb+quad*4+r][q=iq]; c1: +16; c2: +32; c3: +48 (log2 dom.)

      float s0[4], s1[4], s2[4], s3[4];
      float mt = -1e30f;
      #pragma unroll
      for (int r=0;r<4;r++){
        s0[r] = c0[r] + b2f_lo(bmA[r]);
        s1[r] = c1[r] + b2f_hi(bmA[r]);
        s2[r] = c2[r] + b2f_lo(bmB[r]);
        s3[r] = c3[r] + b2f_hi(bmB[r]);
        mt = fmaxf(mt, fmaxf(fmaxf(s0[r], s1[r]), fmaxf(s2[r], s3[r])));
      }
      mt = fmaxf(mt, __shfl_xor(mt, 16));
      mt = fmaxf(mt, __shfl_xor(mt, 32));

      // defer-max: only rescale when the running max grows by > 8 (p <= 2^8)
      if (!__all(mt <= m_s + 8.f)){
        float mn = fmaxf(m_s, mt);
        float al = exp2f(m_s - mn);
        m_s = mn;
        l_s *= al;
        #pragma unroll
        for (int r=0;r<4;r++){
          float alr = __shfl(al, quad*4 + r);
          oc0[r] *= alr; oc1[r] *= alr;
        }
      }

      float rs = 0.f;
      u16 pb0[4], pb1[4], pb2[4], pb3[4];
      #pragma unroll
      for (int r=0;r<4;r++){
        float p0 = exp2f(s0[r] - m_s);
        float p1 = exp2f(s1[r] - m_s);
        float p2 = exp2f(s2[r] - m_s);
        float p3 = exp2f(s3[r] - m_s);
        rs += (p0 + p1) + (p2 + p3);
        pb0[r] = f2b(p0); pb1[r] = f2b(p1); pb2[r] = f2b(p2); pb3[r] = f2b(p3);
      }
      rs += __shfl_xor(rs, 16);
      rs += __shfl_xor(rs, 32);
      l_s += rs;

      // P -> wave-private LDS (16 rows x 8 granules, granule ^= l15&7)
      u64 w0 = (u64)pb0[0] | ((u64)pb0[1]<<16) | ((u64)pb0[2]<<32) | ((u64)pb0[3]<<48);
      u64 w1 = (u64)pb1[0] | ((u64)pb1[1]<<16) | ((u64)pb1[2]<<32) | ((u64)pb1[3]<<48);
      u64 w2 = (u64)pb2[0] | ((u64)pb2[1]<<16) | ((u64)pb2[2]<<32) | ((u64)pb2[3]<<48);
      u64 w3 = (u64)pb3[0] | ((u64)pb3[1]<<16) | ((u64)pb3[2]<<32) | ((u64)pb3[3]<<48);
      *reinterpret_cast<u64*>(&lds[prow + (((0 + q2) ^ swz) << 3) + qh]) = w0;
      *reinterpret_cast<u64*>(&lds[prow + (((2 + q2) ^ swz) << 3) + qh]) = w1;
      *reinterpret_cast<u64*>(&lds[prow + (((4 + q2) ^ swz) << 3) + qh]) = w2;
      *reinterpret_cast<u64*>(&lds[prow + (((6 + q2) ^ swz) << 3) + qh]) = w3;

      short8 pa0 = *reinterpret_cast<const short8*>(&lds[prow + (((quad    ) ^ swz) << 3)]);
      short8 pa1 = *reinterpret_cast<const short8*>(&lds[prow + (((quad + 4) ^ swz) << 3)]);
      short8 vb00 = *reinterpret_cast<const short8*>(&lds[VADDR(     l15, kb      + quad*8)]);
      short8 vb01 = *reinterpret_cast<const short8*>(&lds[VADDR(16 + l15, kb      + quad*8)]);
      short8 vb10 = *reinterpret_cast<const short8*>(&lds[VADDR(     l15, kb + 32 + quad*8)]);
      short8 vb11 = *reinterpret_cast<const short8*>(&lds[VADDR(16 + l15, kb + 32 + quad*8)]);
      __builtin_amdgcn_s_setprio(1);
      oc0 = __builtin_amdgcn_mfma_f32_16x16x32_bf16(pa0, vb00, oc0, 0,0,0);
      oc1 = __builtin_amdgcn_mfma_f32_16x16x32_bf16(pa0, vb01, oc1, 0,0,0);
      oc0 = __builtin_amdgcn_mfma_f32_16x16x32_bf16(pa1, vb10, oc0, 0,0,0);
      oc1 = __builtin_amdgcn_mfma_f32_16x16x32_bf16(pa1, vb11, oc1, 0,0,0);
      __builtin_amdgcn_s_setprio(0);

      #pragma unroll
      for (int r=0;r<4;r++){ bmA[r] = bmAn[r]; bmB[r] = bmBn[r]; }
      kf0 = kn0; kf1 = kn1; kf2 = kn2; kf3 = kn3;
    }

    // tail: keys 384..415 (kf0,kf1,bmA prefetched by it==5 iteration)
    {
      f32x4 z = {0.f,0.f,0.f,0.f};
      f32x4 c0 = __builtin_amdgcn_mfma_f32_16x16x32_bf16(kf0, qf, z, 0,0,0);
      f32x4 c1 = __builtin_amdgcn_mfma_f32_16x16x32_bf16(kf1, qf, z, 0,0,0);
      float s0[4], s1[4];
      float mt = -1e30f;
      #pragma unroll
      for (int r=0;r<4;r++){
        s0[r] = c0[r] + b2f_lo(bmA[r]);
        s1[r] = c1[r] + b2f_hi(bmA[r]);
        mt = fmaxf(mt, fmaxf(s0[r], s1[r]));
      }
      mt = fmaxf(mt, __shfl_xor(mt, 16));
      mt = fmaxf(mt, __shfl_xor(mt, 32));
      if (!__all(mt <= m_s + 8.f)){
        float mn = fmaxf(m_s, mt);
        float al = exp2f(m_s - mn);
        m_s = mn;
        l_s *= al;
        #pragma unroll
        for (int r=0;r<4;r++){
          float alr = __shfl(al, quad*4 + r);
          oc0[r] *= alr; oc1[r] *= alr;
        }
      }
      float rs = 0.f;
      u16 pb0[4], pb1[4];
      #pragma unroll
      for (int r=0;r<4;r++){
        float p0 = exp2f(s0[r] - m_s);
        float p1 = exp2f(s1[r] - m_s);
        rs += p0 + p1;
        pb0[r] = f2b(p0); pb1[r] = f2b(p1);
      }
      rs += __shfl_xor(rs, 16);
      rs += __shfl_xor(rs, 32);
      l_s += rs;
      u64 w0 = (u64)pb0[0] | ((u64)pb0[1]<<16) | ((u64)pb0[2]<<32) | ((u64)pb0[3]<<48);
      u64 w1 = (u64)pb1[0] | ((u64)pb1[1]<<16) | ((u64)pb1[2]<<32) | ((u64)pb1[3]<<48);
      *reinterpret_cast<u64*>(&lds[prow + (((0 + q2) ^ swz) << 3) + qh]) = w0;
      *reinterpret_cast<u64*>(&lds[prow + (((2 + q2) ^ swz) << 3) + qh]) = w1;
      short8 pa0 = *reinterpret_cast<const short8*>(&lds[prow + ((quad ^ swz) << 3)]);
      short8 vb0 = *reinterpret_cast<const short8*>(&lds[VADDR(     l15, 384 + quad*8)]);
      short8 vb1 = *reinterpret_cast<const short8*>(&lds[VADDR(16 + l15, 384 + quad*8)]);
      oc0 = __builtin_amdgcn_mfma_f32_16x16x32_bf16(pa0, vb0, oc0, 0,0,0);
      oc1 = __builtin_amdgcn_mfma_f32_16x16x32_bf16(pa0, vb1, oc1, 0,0,0);
    }

    float inv = 1.f / l_s;
    #pragma unroll
    for (int r=0;r<4;r++){
      float invr = __shfl(inv, quad*4 + r);
      int i = qt*16 + quad*4 + r;
      if (i < LL){
        long o = ((long)(w*LL + i))*CC + head*HDIM;
        out[o + l15]      = f2b(oc0[r]*invr);
        out[o + 16 + l15] = f2b(oc1[r]*invr);
      }
    }
  }
}

extern "C" void kernel_launch(void* const* d_in, const int* in_sizes, int n_in,
                              void* d_out, int out_size, void* d_ws, size_t ws_size,
                              hipStream_t stream)
{
  const float* x     = (const float*)d_in[0];
  const float* ln1g  = (const float*)d_in[1];
  const float* ln1b  = (const float*)d_in[2];
  const float* qkvw  = (const float*)d_in[3];
  const float* qkvb  = (const float*)d_in[4];
  const float* rpb   = (const float*)d_in[5];
  const float* projw = (const float*)d_in[6];
  const float* projb = (const float*)d_in[7];
  const float* ln2g  = (const float*)d_in[8];
  const float* ln2b  = (const float*)d_in[9];
  const float* fc1w  = (const float*)d_in[10];
  const float* fc1b  = (const float*)d_in[11];
  const float* fc2w  = (const float*)d_in[12];
  const float* fc2b  = (const float*)d_in[13];
  float* outf = (float*)d_out;                  // f32 residual stream / output

  u16* buf1 = (u16*)d_ws;                       // bf16 act, NTOK*128
  u16* bufq = buf1 + (size_t)NTOK*CC;           // bf16 qkv / mlp hidden half
  u16* wts  = bufq + (size_t)NTOK*384;          // transposed bf16 weights
  u32* bm   = (u32*)(wts + 393216);             // packed bias+mask table

  for (int blk = 0; blk < 2; ++blk){
    u16* wb = wts + (size_t)blk*196608;
    wt_kernel<<<(49152+255)/256, 256, 0, stream>>>(qkvw + (size_t)blk*128*384, wb,          128, 384, 49152);
    wt_kernel<<<(16384+255)/256, 256, 0, stream>>>(projw + (size_t)blk*128*128, wb+49152,   128, 128, 16384);
    wt_kernel<<<(65536+255)/256, 256, 0, stream>>>(fc1w  + (size_t)blk*128*512, wb+65536,   128, 512, 65536);
    wt_kernel<<<(65536+255)/256, 256, 0, stream>>>(fc2w  + (size_t)blk*512*128, wb+131072,  512, 128, 65536);
  }

  for (int blk = 0; blk < 2; ++blk){
    const int sh = blk;
    const float* resid = (blk==0) ? x : outf;
    u16* wb = wts + (size_t)blk*196608;

    // block 0 (unshifted) only uses mask class 0 -> build 1/8 of the table
    const int bmtot = (blk==0) ? 4*BM_PER_HEAD : BM_TOTAL;
    biasm_kernel<<<(bmtot+255)/256, 256, 0, stream>>>(
        rpb + (size_t)blk*2535*NHEAD, bm, bmtot);
    // LN1 + roll + window-partition gather
    ln_kernel<<<NTOK/4, 256, 0, stream>>>(resid,
        ln1g + blk*CC, ln1b + blk*CC, buf1, 1, sh);
    // QKV GEMM (q pre-scaled by 32^-0.5 * log2e for exp2-domain softmax)
    mm_kernel<128,0><<<dim3(392,3), 256, 0, stream>>>(
        buf1, wb, 128, qkvb + blk*384, bufq, 384,
        nullptr, nullptr, QKSCALE*LOG2E, 0, 0);
    // attention (128 windows x 4 heads), 8 waves/block
    attn_kernel<<<NWIN*NHEAD, 512, 0, stream>>>(bufq, bm, buf1, sh);
    // proj + reverse/roll-back scatter + residual -> outf
    mm_kernel<128,2><<<dim3(392,1), 256, 0, stream>>>(
        buf1, wb+49152, 128, projb + blk*CC, nullptr, 0,
        outf, resid, 1.f, sh, 0);
    // LN2
    ln_kernel<<<NTOK/4, 256, 0, stream>>>(outf,
        ln2g + blk*CC, ln2b + blk*CC, buf1, 0, 0);
    // MLP in 2 column-halves of 256 (hidden half reuses bufq)
    for (int h = 0; h < 2; ++h){
      mm_kernel<128,1><<<dim3(392,2), 256, 0, stream>>>(
          buf1, wb + 65536 + (size_t)h*256*128, 128,
          fc1b + blk*512 + h*256, bufq, 256,
          nullptr, nullptr, 1.f, 0, 0);
      mm_kernel<256,3><<<dim3(392,1), 256, 0, stream>>>(
          bufq, wb + 131072 + h*256, 512,
          fc2b + blk*CC, nullptr, 0,
          outf, nullptr, 1.f, 0, h==0 ? 1 : 0);
    }
  }
}

// Round 3
// 488.522 us; speedup vs baseline: 1.1451x; 1.0341x over previous
//
#include <hip/hip_runtime.h>
#include <hip/hip_bf16.h>
#include <math.h>

// VideoSwinBasicLayer: 2 swin blocks (W-MSA, SW-MSA) on (1,16,56,56,128), NH=4,
// window (8,7,7) -> L=392, nW=128, shift (4,3,3), HID=512. IO f32.
// R10: attn cvt_pk bf16 packing (replaces software f2b+shift/or), K swizzle
// fixed to 2-way (^ (row>>2)&3), V tile stride 512 + (d&7)^((d>>3)&3) swizzle
// with u32-paired staging writes (conflict-free). LN2 fused into proj epilogue,
// LN1(+shifted gather) of blk1 fused into blk0 fc2-h1 epilogue, wt launches
// merged. ws: buf1 12.85MB | bufq 38.5MB | wtsT 0.79MB | bm 10.44MB = 62.6MB.

#define NTOK 50176   // 16*56*56
#define CC   128
#define LL   392
#define NWIN 128
#define NHEAD 4
#define HDIM 32
#define QKSCALE 0.17677669529663687f  // 32^-0.5
#define LOG2E   1.4426950408889634f

// attention LDS layout (u16 units)
#define KOFF    0             // K: 416 rows x 32, 2-way-max XOR swizzle = 13312 u16
#define VOFF    13312         // V_T: 32 x 512 = 16384 u16
#define POFF    29696         // P: 8 waves x 1024 (16 q-rows x 128B, swizzled)
#define LDS_U16 37888         // 75776 B -> 2 blocks/CU

// K tile: row-major [row][32], b128 granule g (0..3) swizzled by row bits 0..3.
#define KADDR(row, g) (((row) << 5) + ((((g) ^ ((row) & 3) ^ (((row) >> 2) & 3))) << 3))
// V tile: [d][512] u16; granule = (k>>3) ^ (d&7) ^ ((d>>3)&3). k must be %8==0.
#define VSW(d) ((((d) & 7)) ^ ((((d) >> 3) & 3)))
#define VADDR(d, k) (VOFF + ((d) << 9) + (((((k) >> 3)) ^ VSW(d)) << 3))

#define BM_PER_HEAD (13*16*392)            // u32 per (cls,head) slice
#define BM_TOTAL    (8*4*BM_PER_HEAD)      // 10.44 MB

typedef unsigned short u16;
typedef unsigned int   u32;
typedef unsigned long long u64;
typedef __attribute__((ext_vector_type(8))) short short8;
typedef __attribute__((ext_vector_type(4))) float f32x4;
typedef __attribute__((ext_vector_type(2))) unsigned int u32x2;

// async global->LDS, 16B per lane; LDS dest = wave-uniform base + lane*16.
#define GLDS(gp, lp) __builtin_amdgcn_global_load_lds( \
    (const __attribute__((address_space(1))) void*)(gp), \
    (__attribute__((address_space(3))) void*)(lp), 16, 0, 0)

__device__ __forceinline__ float b2f_lo(u32 u){ return __uint_as_float(u<<16); }
__device__ __forceinline__ float b2f_hi(u32 u){ return __uint_as_float(u & 0xffff0000u); }
__device__ __forceinline__ u16 f2b(float f){
  __hip_bfloat16 h = __float2bfloat16(f);
  return *reinterpret_cast<u16*>(&h);
}
// pack 2 f32 -> 2 bf16 (RNE) in one instruction; lo->bits[15:0], hi->bits[31:16]
__device__ __forceinline__ u32 cvtpk(float lo, float hi){
  u32 r; asm("v_cvt_pk_bf16_f32 %0, %1, %2" : "=v"(r) : "v"(lo), "v"(hi)); return r;
}

// window-ordered row r -> flat token position (roll(+shift) both directions).
__device__ __forceinline__ int row_to_pos(int r, int shifted){
  int w = r / LL, t = r - w*LL;
  int wd = w >> 6, wh = (w >> 3) & 7, ww = w & 7;
  int td = t / 49, rem = t - td*49, th = rem / 7, tw = rem - th*7;
  int d = wd*8 + td, h = wh*7 + th, x = ww*7 + tw;
  if (shifted){ d = (d+4)&15; h += 3; if (h>=56) h-=56; x += 3; if (x>=56) x-=56; }
  return (d*56 + h)*56 + x;
}

// inverse of row_to_pos with shifted=1: flat token position -> window row.
__device__ __forceinline__ int pos_to_row_sh(int p){
  int d = p / 3136, rem = p - d*3136, h = rem / 56, x = rem - h*56;
  d = (d + 12) & 15; h -= 3; if (h < 0) h += 56; x -= 3; if (x < 0) x += 56;
  int wd = d >> 3, td = d & 7;
  int wh = h / 7, th = h - wh*7, ww = x / 7, tw = x - ww*7;
  return (wd*64 + wh*8 + ww)*LL + td*49 + th*7 + tw;
}

// LayerNorm over C=128 (f32 src), bf16 out. One wave per row.
__global__ __launch_bounds__(256) void ln_kernel(
    const float* __restrict__ xf, const float* __restrict__ g,
    const float* __restrict__ b, u16* __restrict__ out, int do_map, int shifted)
{
  int wave = threadIdx.x >> 6, lane = threadIdx.x & 63;
  int r = blockIdx.x*4 + wave;
  int pos = do_map ? row_to_pos(r, shifted) : r;
  long src = (long)pos * CC;
  float v0 = xf[src+lane], v1 = xf[src+64+lane];
  float s = v0+v1, ss = v0*v0 + v1*v1;
  #pragma unroll
  for (int o=32; o>0; o>>=1){ s += __shfl_xor(s,o); ss += __shfl_xor(ss,o); }
  float mean = s*(1.f/CC);
  float var  = ss*(1.f/CC) - mean*mean;
  float rstd = rsqrtf(var + 1e-5f);
  long dst = (long)r*CC;
  out[dst + lane]      = f2b((v0-mean)*rstd*g[lane]    + b[lane]);
  out[dst + 64 + lane] = f2b((v1-mean)*rstd*g[64+lane] + b[64+lane]);
}

// All 8 weight transposes (2 blocks x {qkv,proj,fc1,fc2}) in one launch.
// out layout per block (u16): [0,49152) qkvT, [49152,65536) projT,
// [65536,131072) fc1T, [131072,196608) fc2T.
__global__ __launch_bounds__(256) void wtall_kernel(
    const float* __restrict__ qkvw, const float* __restrict__ projw,
    const float* __restrict__ fc1w, const float* __restrict__ fc2w,
    u16* __restrict__ wts)
{
  int t = blockIdx.x*256 + threadIdx.x;               // 0..393215
  int blk = t / 196608, r = t - blk*196608;
  const float* in; int Kd, Nd, off;
  if (r < 49152)      { in = qkvw + (size_t)blk*49152; Kd = 128; Nd = 384; off = r; }
  else if (r < 65536) { in = projw + (size_t)blk*16384; Kd = 128; Nd = 128; off = r - 49152; }
  else if (r < 131072){ in = fc1w + (size_t)blk*65536;  Kd = 128; Nd = 512; off = r - 65536; }
  else                { in = fc2w + (size_t)blk*65536;  Kd = 512; Nd = 128; off = r - 131072; }
  int n = off / Kd, k = off - n*Kd;
  wts[t] = f2b(in[k*Nd + n]);
}

// Packed bias(+mask) table in exp2 domain: bm[cls][h][s][jj][i] u32 =
// (bf16 v(j=s*32+jj, i), bf16 v(j+16, i)).
// v = (rpb-bias - 100*maskneq(cls)) * log2e;  j>=392 -> -1e30.
// total = ncls*4*BM_PER_HEAD (block 0 only needs cls=0).
__global__ __launch_bounds__(256) void biasm_kernel(
    const float* __restrict__ rpb, u32* __restrict__ bm, int total)
{
  int t = blockIdx.x*256 + threadIdx.x;
  if (t >= total) return;
  int i = t % 392; int rest = t / 392;
  int jj = rest % 16; rest /= 16;
  int s  = rest % 13; rest /= 13;
  int h  = rest % 4;  int cls = rest / 4;
  int tdi=i/49, rmi=i-tdi*49, thi=rmi/7, twi=rmi-thi*7;
  u32 pack = 0;
  #pragma unroll
  for (int half=0; half<2; half++){
    int j = s*32 + jj + half*16;
    float v = -1e30f;
    if (j < LL){
      int tdj=j/49, rmj=j-tdj*49, thj=rmj/7, twj=rmj-thj*7;
      int idx = (tdi-tdj)*169 + (thi-thj)*13 + (twi-twj) + 1267;
      v = rpb[idx*NHEAD + h];
      bool neq = ((cls&4) && ((tdi<4) != (tdj<4)))
              || ((cls&2) && ((thi<4) != (thj<4)))
              || ((cls&1) && ((twi<4) != (twj<4)));
      if (neq) v -= 100.f;
      v *= LOG2E;
    }
    pack |= ((u32)f2b(v)) << (16*half);
  }
  bm[t] = pack;
}

// MFMA GEMM, m97-style staging: C[128x128] = A[rows x KD](bf16) @ Wt^T.
// EPI: 0 = (+bias)*scale -> bf16 | 1 = +bias, GELU -> bf16
//      2 = +bias, scatter, +Res -> f32 | 3 = accum f32
// LNF: 0 = none | 1 = (EPI2) fuse LN -> OutB at scattered pos
//      2 = (EPI3) fuse LN -> OutB at shifted-window-gathered row
template<int KD, int EPI, int LNF>
__global__ __launch_bounds__(256) void mm_kernel(
    const u16* __restrict__ A, const u16* __restrict__ Wt, int ldw,
    const float* __restrict__ bias, u16* __restrict__ OutB, int ldo,
    float* __restrict__ OutF, const float* __restrict__ Res,
    const float* __restrict__ lng, const float* __restrict__ lnb,
    float scaleq, int shifted, int use_bias)
{
  __shared__ __align__(16) u16 As[128*32];
  __shared__ __align__(16) u16 Bs[128*32];
  const int tid = threadIdx.x, lane = tid & 63, wv = tid >> 6;
  const int quad = lane >> 4, l15 = lane & 15;
  const int rh = wv >> 1, ch = wv & 1;
  const int r0 = blockIdx.x * 128, n0 = blockIdx.y * 128;
  const int srow = lane >> 2, spart = (lane & 3) * 8;  // staging: 16 rows/issue

  f32x4 acc[4][4] = {};

  for (int kt = 0; kt < KD/32; kt++){
    const int k0 = kt*32;
    #pragma unroll
    for (int t=0;t<2;t++){
      const int rowbase = wv*32 + t*16;
      GLDS(&A [(long)(r0 + rowbase + srow)*KD  + k0 + spart], &As[rowbase*32]);
      GLDS(&Wt[(long)(n0 + rowbase + srow)*ldw + k0 + spart], &Bs[rowbase*32]);
    }
    __syncthreads();
    short8 af[4], bf[4];
    #pragma unroll
    for (int rt=0;rt<4;rt++)
      af[rt] = *reinterpret_cast<const short8*>(&As[(rh*64 + rt*16 + l15)*32 + quad*8]);
    #pragma unroll
    for (int ct=0;ct<4;ct++)
      bf[ct] = *reinterpret_cast<const short8*>(&Bs[(ch*64 + ct*16 + l15)*32 + quad*8]);
    #pragma unroll
    for (int rt=0;rt<4;rt++)
      #pragma unroll
      for (int ct=0;ct<4;ct++)
        acc[rt][ct] = __builtin_amdgcn_mfma_f32_16x16x32_bf16(af[rt], bf[ct], acc[rt][ct], 0,0,0);
    __syncthreads();
  }

  if (LNF == 0){
    #pragma unroll
    for (int rt=0;rt<4;rt++){
      #pragma unroll
      for (int rr=0;rr<4;rr++){
        const int row_g = r0 + rh*64 + rt*16 + quad*4 + rr;
        long pos = 0;
        if (EPI == 2) pos = (long)row_to_pos(row_g, shifted) * CC;
        #pragma unroll
        for (int ct=0;ct<4;ct++){
          const int col_g = n0 + ch*64 + ct*16 + l15;
          float v = acc[rt][ct][rr];
          if (EPI == 0){
            float sc = (blockIdx.y == 0) ? scaleq : 1.f;
            v = (v + bias[col_g]) * sc;
            OutB[(long)row_g*ldo + col_g] = f2b(v);
          } else if (EPI == 1){
            v += bias[col_g];
            v = 0.5f*v*(1.f + erff(v*0.70710678118654752f));
            OutB[(long)row_g*ldo + col_g] = f2b(v);
          } else if (EPI == 2){
            OutF[pos + col_g] = Res[pos + col_g] + v + bias[col_g];
          } else {
            float o = OutF[(long)row_g*CC + col_g] + v;
            if (use_bias) o += bias[col_g];
            OutF[(long)row_g*CC + col_g] = o;
          }
        }
      }
    }
  } else {
    // fused LayerNorm epilogue (requires full 128-col rows: gridDim.y == 1).
    float* red = (float*)As;     // [128 rows][2 ch][2 stats] = 2KB, reuse As
    int pose[4][4];
    #pragma unroll
    for (int rt=0;rt<4;rt++){
      #pragma unroll
      for (int rr=0;rr<4;rr++){
        const int row_g = r0 + rh*64 + rt*16 + quad*4 + rr;
        int pos = (EPI == 2) ? row_to_pos(row_g, shifted) : row_g;
        pose[rt][rr] = pos;
        long pb = (long)pos * CC;
        float s = 0.f, ss = 0.f;
        #pragma unroll
        for (int ct=0;ct<4;ct++){
          const int col_g = n0 + ch*64 + ct*16 + l15;
          float v = acc[rt][ct][rr];
          float o;
          if (EPI == 2) o = Res[pb + col_g] + v + bias[col_g];
          else { o = OutF[pb + col_g] + v; if (use_bias) o += bias[col_g]; }
          OutF[pb + col_g] = o;
          acc[rt][ct][rr] = o;
          s += o; ss += o*o;
        }
        #pragma unroll
        for (int off=1; off<16; off<<=1){
          s  += __shfl_xor(s,  off);
          ss += __shfl_xor(ss, off);
        }
        if (l15 == 0){
          int rl = rh*64 + rt*16 + quad*4 + rr;
          red[rl*4 + ch*2]     = s;
          red[rl*4 + ch*2 + 1] = ss;
        }
      }
    }
    __syncthreads();
    #pragma unroll
    for (int rt=0;rt<4;rt++){
      #pragma unroll
      for (int rr=0;rr<4;rr++){
        const int rl = rh*64 + rt*16 + quad*4 + rr;
        float st  = red[rl*4]     + red[rl*4 + 2];
        float sst = red[rl*4 + 1] + red[rl*4 + 3];
        float mean = st*(1.f/128.f);
        float var  = sst*(1.f/128.f) - mean*mean;
        float rstd = rsqrtf(var + 1e-5f);
        long oidx;
        if (LNF == 1) oidx = (long)pose[rt][rr] * CC;            // linear-pos out
        else          oidx = (long)pos_to_row_sh(pose[rt][rr]) * CC; // window out
        #pragma unroll
        for (int ct=0;ct<4;ct++){
          const int col_g = n0 + ch*64 + ct*16 + l15;
          float val = (acc[rt][ct][rr] - mean)*rstd*lng[col_g] + lnb[col_g];
          OutB[oidx + col_g] = f2b(val);
        }
      }
    }
  }
}

// MFMA flash attention, S^T orientation. One block per (window, head); 8 waves
// x 16-row q-tiles (qt += 8). 64-key softmax steps: joint max/exp/sum and a
// single P LDS round-trip per 64 keys. exp2-domain state, defer-max (THR=8).
// P pack via v_cvt_pk_bf16_f32. All LDS paths <=2-way bank aliasing.
__global__ __launch_bounds__(512, 4) void attn_kernel(
    const u16* __restrict__ qkv, const u32* __restrict__ bm,
    u16* __restrict__ out, int shifted)
{
  __shared__ __align__(16) u16 lds[LDS_U16];

  const int w = blockIdx.x >> 2, head = blockIdx.x & 3;
  const int tid = threadIdx.x, lane = tid & 63, wave = tid >> 6;
  const int quad = lane >> 4, l15 = lane & 15;
  const long qkvbase = (long)w * LL * 384;
  const int wd = w>>6, wh = (w>>3)&7, ww = w&7;
  const int cls = shifted ? (((wd!=0)?4:0) | ((wh==7)?2:0) | ((ww==7)?1:0)) : 0;
  const u32* __restrict__ bmh = bm + (size_t)(cls*NHEAD + head)*BM_PER_HEAD;
  const int pbase = POFF + wave*1024;
  const int swz = l15 & 7;
  const int prow = pbase + l15*64;
  const int q2 = quad >> 1, qh = (quad & 1) << 2;

  // stage K (rows 392..415 zeroed), XOR swizzle (2-way max)
  for (int idx = tid; idx < 416*4; idx += 512){
    int key = idx >> 2, part = idx & 3;
    short8 val = {0,0,0,0,0,0,0,0};
    if (key < LL)
      val = *reinterpret_cast<const short8*>(&qkv[qkvbase + (long)key*384 + 128 + head*HDIM + part*8]);
    *reinterpret_cast<short8*>(&lds[KOFF + KADDR(key, part)]) = val;
  }
  // stage V transposed, u32-paired (keys 2kp,2kp+1 packed into one dword)
  for (int idx = tid; idx < 208*4; idx += 512){
    int kp = idx >> 2, dbase = (idx & 3) * 8;
    int key0 = kp*2;
    short8 a = {0,0,0,0,0,0,0,0}, b = {0,0,0,0,0,0,0,0};
    if (key0 < LL){
      a = *reinterpret_cast<const short8*>(&qkv[qkvbase + (long)key0*384 + 256 + head*HDIM + dbase]);
      b = *reinterpret_cast<const short8*>(&qkv[qkvbase + (long)(key0+1)*384 + 256 + head*HDIM + dbase]);
    }
    #pragma unroll
    for (int j=0;j<8;j++){
      int d = dbase + j;
      u32 v = (u32)(u16)((const u16*)&a)[j] | ((u32)(u16)((const u16*)&b)[j] << 16);
      *reinterpret_cast<u32*>(&lds[VOFF + (d<<9) + ((((kp>>2) ^ VSW(d))) << 3) + ((kp&3)<<1)]) = v;
    }
  }
  __syncthreads();

  for (int qt = wave; qt < 25; qt += 8){
    int iq = qt*16 + l15; if (iq > LL-1) iq = LL-1;
    short8 qf = *reinterpret_cast<const short8*>(&qkv[qkvbase + (long)iq*384 + head*HDIM + quad*8]);

    float m_s = -1e30f, l_s = 0.f;
    f32x4 oc0 = {0.f,0.f,0.f,0.f}, oc1 = {0.f,0.f,0.f,0.f};

    // prefetch it=0: 4 K-frags + 2 bm chunks
    u32 bmA[4], bmB[4];
    {
      const u32* bp = &bmh[iq];
      #pragma unroll
      for (int r=0;r<4;r++) bmA[r] = bp[(      quad*4 + r)*392];
      #pragma unroll
      for (int r=0;r<4;r++) bmB[r] = bp[(16 + quad*4 + r)*392];
    }
    short8 kf0 = *reinterpret_cast<const short8*>(&lds[KOFF + KADDR(     l15, quad)]);
    short8 kf1 = *reinterpret_cast<const short8*>(&lds[KOFF + KADDR(16 + l15, quad)]);
    short8 kf2 = *reinterpret_cast<const short8*>(&lds[KOFF + KADDR(32 + l15, quad)]);
    short8 kf3 = *reinterpret_cast<const short8*>(&lds[KOFF + KADDR(48 + l15, quad)]);

    for (int it = 0; it < 6; it++){
      const int kb = it*64;
      // prefetch next 64-key group (or the 32-key tail when it==5)
      u32 bmAn[4] = {}, bmBn[4] = {};
      short8 kn0 = {}, kn1 = {}, kn2 = {}, kn3 = {};
      if (it < 5){
        const u32* bp = &bmh[(size_t)((2*it+2)*16)*392 + iq];
        #pragma unroll
        for (int r=0;r<4;r++) bmAn[r] = bp[(      quad*4 + r)*392];
        #pragma unroll
        for (int r=0;r<4;r++) bmBn[r] = bp[(16 + quad*4 + r)*392];
        kn0 = *reinterpret_cast<const short8*>(&lds[KOFF + KADDR(kb + 64 + l15, quad)]);
        kn1 = *reinterpret_cast<const short8*>(&lds[KOFF + KADDR(kb + 80 + l15, quad)]);
        kn2 = *reinterpret_cast<const short8*>(&lds[KOFF + KADDR(kb + 96 + l15, quad)]);
        kn3 = *reinterpret_cast<const short8*>(&lds[KOFF + KADDR(kb +112 + l15, quad)]);
      } else {
        const u32* bp = &bmh[(size_t)(12*16)*392 + iq];
        #pragma unroll
        for (int r=0;r<4;r++) bmAn[r] = bp[(quad*4 + r)*392];
        kn0 = *reinterpret_cast<const short8*>(&lds[KOFF + KADDR(384 + l15, quad)]);
        kn1 = *reinterpret_cast<const short8*>(&lds[KOFF + KADDR(400 + l15, quad)]);
      }

      f32x4 z = {0.f,0.f,0.f,0.f};
      __builtin_amdgcn_s_setprio(1);
      f32x4 c0 = __builtin_amdgcn_mfma_f32_16x16x32_bf16(kf0, qf, z, 0,0,0);
      f32x4 c1 = __builtin_amdgcn_mfma_f32_16x16x32_bf16(kf1, qf, z, 0,0,0);
      f32x4 c2 = __builtin_amdgcn_mfma_f32_16x16x32_bf16(kf2, qf, z, 0,0,0);
      f32x4 c3 = __builtin_amdgcn_mfma_f32_16x16x32_bf16(kf3, qf, z, 0,0,0);
      __builtin_amdgcn_s_setprio(0);
      // c0[r]: S[key=kb+quad*4+r][q=iq]; c1: +16; c2: +32; c3: +48 (log2 dom.)

      float s0[4], s1[4], s2[4], s3[4];
      float mt = -1e30f;
      #pragma unroll
      for (int r=0;r<4;r++){
        s0[r] = c0[r] + b2f_lo(bmA[r]);
        s1[r] = c1[r] + b2f_hi(bmA[r]);
        s2[r] = c2[r] + b2f_lo(bmB[r]);
        s3[r] = c3[r] + b2f_hi(bmB[r]);
        mt = fmaxf(mt, fmaxf(fmaxf(s0[r], s1[r]), fmaxf(s2[r], s3[r])));
      }
      mt = fmaxf(mt, __shfl_xor(mt, 16));
      mt = fmaxf(mt, __shfl_xor(mt, 32));

      // defer-max: only rescale when the running max grows by > 8 (p <= 2^8)
      if (!__all(mt <= m_s + 8.f)){
        float mn = fmaxf(m_s, mt);
        float al = exp2f(m_s - mn);
        m_s = mn;
        l_s *= al;
        #pragma unroll
        for (int r=0;r<4;r++){
          float alr = __shfl(al, quad*4 + r);
          oc0[r] *= alr; oc1[r] *= alr;
        }
      }

      float rs = 0.f;
      float p0[4], p1[4], p2[4], p3[4];
      #pragma unroll
      for (int r=0;r<4;r++){
        p0[r] = exp2f(s0[r] - m_s);
        p1[r] = exp2f(s1[r] - m_s);
        p2[r] = exp2f(s2[r] - m_s);
        p3[r] = exp2f(s3[r] - m_s);
        rs += (p0[r] + p1[r]) + (p2[r] + p3[r]);
      }
      rs += __shfl_xor(rs, 16);
      rs += __shfl_xor(rs, 32);
      l_s += rs;

      // P -> wave-private LDS (16 rows x 8 granules, granule ^= l15&7)
      u32x2 w0, w1, w2, w3;
      w0.x = cvtpk(p0[0], p0[1]); w0.y = cvtpk(p0[2], p0[3]);
      w1.x = cvtpk(p1[0], p1[1]); w1.y = cvtpk(p1[2], p1[3]);
      w2.x = cvtpk(p2[0], p2[1]); w2.y = cvtpk(p2[2], p2[3]);
      w3.x = cvtpk(p3[0], p3[1]); w3.y = cvtpk(p3[2], p3[3]);
      *reinterpret_cast<u32x2*>(&lds[prow + (((0 + q2) ^ swz) << 3) + qh]) = w0;
      *reinterpret_cast<u32x2*>(&lds[prow + (((2 + q2) ^ swz) << 3) + qh]) = w1;
      *reinterpret_cast<u32x2*>(&lds[prow + (((4 + q2) ^ swz) << 3) + qh]) = w2;
      *reinterpret_cast<u32x2*>(&lds[prow + (((6 + q2) ^ swz) << 3) + qh]) = w3;

      short8 pa0 = *reinterpret_cast<const short8*>(&lds[prow + (((quad    ) ^ swz) << 3)]);
      short8 pa1 = *reinterpret_cast<const short8*>(&lds[prow + (((quad + 4) ^ swz) << 3)]);
      short8 vb00 = *reinterpret_cast<const short8*>(&lds[VADDR(     l15, kb      + quad*8)]);
      short8 vb01 = *reinterpret_cast<const short8*>(&lds[VADDR(16 + l15, kb      + quad*8)]);
      short8 vb10 = *reinterpret_cast<const short8*>(&lds[VADDR(     l15, kb + 32 + quad*8)]);
      short8 vb11 = *reinterpret_cast<const short8*>(&lds[VADDR(16 + l15, kb + 32 + quad*8)]);
      __builtin_amdgcn_s_setprio(1);
      oc0 = __builtin_amdgcn_mfma_f32_16x16x32_bf16(pa0, vb00, oc0, 0,0,0);
      oc1 = __builtin_amdgcn_mfma_f32_16x16x32_bf16(pa0, vb01, oc1, 0,0,0);
      oc0 = __builtin_amdgcn_mfma_f32_16x16x32_bf16(pa1, vb10, oc0, 0,0,0);
      oc1 = __builtin_amdgcn_mfma_f32_16x16x32_bf16(pa1, vb11, oc1, 0,0,0);
      __builtin_amdgcn_s_setprio(0);

      #pragma unroll
      for (int r=0;r<4;r++){ bmA[r] = bmAn[r]; bmB[r] = bmBn[r]; }
      kf0 = kn0; kf1 = kn1; kf2 = kn2; kf3 = kn3;
    }

    // tail: keys 384..415 (kf0,kf1,bmA prefetched by it==5 iteration)
    {
      f32x4 z = {0.f,0.f,0.f,0.f};
      f32x4 c0 = __builtin_amdgcn_mfma_f32_16x16x32_bf16(kf0, qf, z, 0,0,0);
      f32x4 c1 = __builtin_amdgcn_mfma_f32_16x16x32_bf16(kf1, qf, z, 0,0,0);
      float s0[4], s1[4];
      float mt = -1e30f;
      #pragma unroll
      for (int r=0;r<4;r++){
        s0[r] = c0[r] + b2f_lo(bmA[r]);
        s1[r] = c1[r] + b2f_hi(bmA[r]);
        mt = fmaxf(mt, fmaxf(s0[r], s1[r]));
      }
      mt = fmaxf(mt, __shfl_xor(mt, 16));
      mt = fmaxf(mt, __shfl_xor(mt, 32));
      if (!__all(mt <= m_s + 8.f)){
        float mn = fmaxf(m_s, mt);
        float al = exp2f(m_s - mn);
        m_s = mn;
        l_s *= al;
        #pragma unroll
        for (int r=0;r<4;r++){
          float alr = __shfl(al, quad*4 + r);
          oc0[r] *= alr; oc1[r] *= alr;
        }
      }
      float rs = 0.f;
      float p0[4], p1[4];
      #pragma unroll
      for (int r=0;r<4;r++){
        p0[r] = exp2f(s0[r] - m_s);
        p1[r] = exp2f(s1[r] - m_s);
        rs += p0[r] + p1[r];
      }
      rs += __shfl_xor(rs, 16);
      rs += __shfl_xor(rs, 32);
      l_s += rs;
      u32x2 w0, w1;
      w0.x = cvtpk(p0[0], p0[1]); w0.y = cvtpk(p0[2], p0[3]);
      w1.x = cvtpk(p1[0], p1[1]); w1.y = cvtpk(p1[2], p1[3]);
      *reinterpret_cast<u32x2*>(&lds[prow + (((0 + q2) ^ swz) << 3) + qh]) = w0;
      *reinterpret_cast<u32x2*>(&lds[prow + (((2 + q2) ^ swz) << 3) + qh]) = w1;
      short8 pa0 = *reinterpret_cast<const short8*>(&lds[prow + ((quad ^ swz) << 3)]);
      short8 vb0 = *reinterpret_cast<const short8*>(&lds[VADDR(     l15, 384 + quad*8)]);
      short8 vb1 = *reinterpret_cast<const short8*>(&lds[VADDR(16 + l15, 384 + quad*8)]);
      oc0 = __builtin_amdgcn_mfma_f32_16x16x32_bf16(pa0, vb0, oc0, 0,0,0);
      oc1 = __builtin_amdgcn_mfma_f32_16x16x32_bf16(pa0, vb1, oc1, 0,0,0);
    }

    float inv = 1.f / l_s;
    #pragma unroll
    for (int r=0;r<4;r++){
      float invr = __shfl(inv, quad*4 + r);
      int i = qt*16 + quad*4 + r;
      if (i < LL){
        long o = ((long)(w*LL + i))*CC + head*HDIM;
        out[o + l15]      = f2b(oc0[r]*invr);
        out[o + 16 + l15] = f2b(oc1[r]*invr);
      }
    }
  }
}

extern "C" void kernel_launch(void* const* d_in, const int* in_sizes, int n_in,
                              void* d_out, int out_size, void* d_ws, size_t ws_size,
                              hipStream_t stream)
{
  const float* x     = (const float*)d_in[0];
  const float* ln1g  = (const float*)d_in[1];
  const float* ln1b  = (const float*)d_in[2];
  const float* qkvw  = (const float*)d_in[3];
  const float* qkvb  = (const float*)d_in[4];
  const float* rpb   = (const float*)d_in[5];
  const float* projw = (const float*)d_in[6];
  const float* projb = (const float*)d_in[7];
  const float* ln2g  = (const float*)d_in[8];
  const float* ln2b  = (const float*)d_in[9];
  const float* fc1w  = (const float*)d_in[10];
  const float* fc1b  = (const float*)d_in[11];
  const float* fc2w  = (const float*)d_in[12];
  const float* fc2b  = (const float*)d_in[13];
  float* outf = (float*)d_out;                  // f32 residual stream / output

  u16* buf1 = (u16*)d_ws;                       // bf16 act (window space), NTOK*128
  u16* bufq = buf1 + (size_t)NTOK*CC;           // bf16 qkv / hidden / ln2-out
  u16* ln2o = bufq + (size_t)NTOK*256;          // LN2 output (linear space)
  u16* wts  = bufq + (size_t)NTOK*384;          // transposed bf16 weights
  u32* bm   = (u32*)(wts + 393216);             // packed bias+mask table

  // all weight transposes in one launch
  wtall_kernel<<<1536, 256, 0, stream>>>(qkvw, projw, fc1w, fc2w, wts);

  for (int blk = 0; blk < 2; ++blk){
    const int sh = blk;
    const float* resid = (blk==0) ? x : outf;
    u16* wb = wts + (size_t)blk*196608;

    // block 0 (unshifted) only uses mask class 0 -> build 1/8 of the table
    const int bmtot = (blk==0) ? 4*BM_PER_HEAD : BM_TOTAL;
    biasm_kernel<<<(bmtot+255)/256, 256, 0, stream>>>(
        rpb + (size_t)blk*2535*NHEAD, bm, bmtot);
    // LN1 + roll + window gather: separate kernel only for block 0 (from x);
    // block 1's LN1 is fused into block 0's fc2-h1 epilogue.
    if (blk == 0)
      ln_kernel<<<NTOK/4, 256, 0, stream>>>(resid,
          ln1g, ln1b, buf1, 1, 0);
    // QKV GEMM (q pre-scaled by 32^-0.5 * log2e for exp2-domain softmax)
    mm_kernel<128,0,0><<<dim3(392,3), 256, 0, stream>>>(
        buf1, wb, 128, qkvb + blk*384, bufq, 384,
        nullptr, nullptr, nullptr, nullptr, QKSCALE*LOG2E, 0, 0);
    // attention (128 windows x 4 heads), 8 waves/block
    attn_kernel<<<NWIN*NHEAD, 512, 0, stream>>>(bufq, bm, buf1, sh);
    // proj + reverse/roll-back scatter + residual -> outf; fused LN2 -> ln2o
    mm_kernel<128,2,1><<<dim3(392,1), 256, 0, stream>>>(
        buf1, wb+49152, 128, projb + blk*CC, ln2o, 0,
        outf, resid, ln2g + blk*CC, ln2b + blk*CC, 1.f, sh, 0);
    // MLP in 2 column-halves of 256 (hidden reuses bufq rows x 256)
    for (int h = 0; h < 2; ++h){
      mm_kernel<128,1,0><<<dim3(392,2), 256, 0, stream>>>(
          ln2o, wb + 65536 + (size_t)h*256*128, 128,
          fc1b + blk*512 + h*256, bufq, 256,
          nullptr, nullptr, nullptr, nullptr, 1.f, 0, 0);
      if (h == 0){
        mm_kernel<256,3,0><<<dim3(392,1), 256, 0, stream>>>(
            bufq, wb + 131072, 512,
            fc2b + blk*CC, nullptr, 0,
            outf, nullptr, nullptr, nullptr, 1.f, 0, 1);
      } else if (blk == 0){
        // final fc2 half of block 0: fuse LN1(+shifted window gather) for blk1
        mm_kernel<256,3,2><<<dim3(392,1), 256, 0, stream>>>(
            bufq, wb + 131072 + 256, 512,
            fc2b, buf1, 0,
            outf, nullptr, ln1g + CC, ln1b + CC, 1.f, 0, 0);
      } else {
        mm_kernel<256,3,0><<<dim3(392,1), 256, 0, stream>>>(
            bufq, wb + 131072 + 256, 512,
            fc2b + CC, nullptr, 0,
            outf, nullptr, nullptr, nullptr, 1.f, 0, 0);
      }
    }
  }
}

// Round 4
// 480.794 us; speedup vs baseline: 1.1635x; 1.0161x over previous
//
#include <hip/hip_runtime.h>
#include <hip/hip_bf16.h>
#include <math.h>

// VideoSwinBasicLayer: 2 swin blocks (W-MSA, SW-MSA) on (1,16,56,56,128), NH=4,
// window (8,7,7) -> L=392, nW=128, shift (4,3,3), HID=512. IO f32.
// R11: qkv GEMM epilogue emits attention-ready tiles (Q [row][128]; K packed
// [w,h][392][32] with read-swizzle baked into the global write; V^T [w,h][32][392])
// -> attn stages K/V via pure linear global_load_lds (no scatter staging, no
// staging conflicts). Softmax: defer-max check on UNreduced per-lane max,
// per-lane partial denominator reduced once per q-tile (0 shfls/group steady
// state). bm table repacked [s][i][jj] -> 2 coalesced dwordx4 loads per group.
// ws unchanged: buf1 12.85MB | bufq 38.5MB | wtsT 0.79MB | bm 10.44MB = 62.6MB.

#define NTOK 50176   // 16*56*56
#define CC   128
#define LL   392
#define NWIN 128
#define NHEAD 4
#define HDIM 32
#define QKSCALE 0.17677669529663687f  // 32^-0.5
#define LOG2E   1.4426950408889634f

// attention LDS layout (u16 units)
#define KOFF    0             // K: 392 rows x 32 (granule-swizzled) = 12544 u16
#define VOFF    12544         // V^T: 32 x 392 = 12544 u16
#define POFF    25088         // P: 8 waves x 1024 (16 q-rows x 128B, swizzled)
#define LDS_U16 33280         // 66560 B -> 2 blocks/CU

#define KTILE   12544         // u16 per (w,head) K or V tile

// K tile: row-major [row][32], b128 granule g (0..3) swizzled by row bits 0..3.
// Same formula on the global-write side (mm epilogue) and LDS-read side.
#define KADDR(row, g) (((row) << 5) + ((((g) ^ ((row) & 3) ^ (((row) >> 2) & 3))) << 3))
// V^T tile: [d][392] u16, linear. stride 392 u16 = 196 dw = 4 mod 32 -> 2-way max.
#define VADDR(d, k) (VOFF + (d)*392 + (k))

#define BM_PER_HEAD (13*392*16)            // u32 per (cls,head) slice
#define BM_TOTAL    (8*4*BM_PER_HEAD)      // 10.44 MB

typedef unsigned short u16;
typedef unsigned int   u32;
typedef unsigned long long u64;
typedef __attribute__((ext_vector_type(8))) short short8;
typedef __attribute__((ext_vector_type(4))) float f32x4;
typedef __attribute__((ext_vector_type(2))) unsigned int u32x2;
typedef __attribute__((ext_vector_type(4))) unsigned int u32x4;

// async global->LDS, 16B per lane; LDS dest = wave-uniform base + lane*16.
#define GLDS(gp, lp) __builtin_amdgcn_global_load_lds( \
    (const __attribute__((address_space(1))) void*)(gp), \
    (__attribute__((address_space(3))) void*)(lp), 16, 0, 0)

__device__ __forceinline__ float b2f_lo(u32 u){ return __uint_as_float(u<<16); }
__device__ __forceinline__ float b2f_hi(u32 u){ return __uint_as_float(u & 0xffff0000u); }
__device__ __forceinline__ u16 f2b(float f){
  __hip_bfloat16 h = __float2bfloat16(f);
  return *reinterpret_cast<u16*>(&h);
}
// pack 2 f32 -> 2 bf16 (RNE) in one instruction; lo->bits[15:0], hi->bits[31:16]
__device__ __forceinline__ u32 cvtpk(float lo, float hi){
  u32 r; asm("v_cvt_pk_bf16_f32 %0, %1, %2" : "=v"(r) : "v"(lo), "v"(hi)); return r;
}

// window-ordered row r -> flat token position (roll(+shift) both directions).
__device__ __forceinline__ int row_to_pos(int r, int shifted){
  int w = r / LL, t = r - w*LL;
  int wd = w >> 6, wh = (w >> 3) & 7, ww = w & 7;
  int td = t / 49, rem = t - td*49, th = rem / 7, tw = rem - th*7;
  int d = wd*8 + td, h = wh*7 + th, x = ww*7 + tw;
  if (shifted){ d = (d+4)&15; h += 3; if (h>=56) h-=56; x += 3; if (x>=56) x-=56; }
  return (d*56 + h)*56 + x;
}

// inverse of row_to_pos with shifted=1: flat token position -> window row.
__device__ __forceinline__ int pos_to_row_sh(int p){
  int d = p / 3136, rem = p - d*3136, h = rem / 56, x = rem - h*56;
  d = (d + 12) & 15; h -= 3; if (h < 0) h += 56; x -= 3; if (x < 0) x += 56;
  int wd = d >> 3, td = d & 7;
  int wh = h / 7, th = h - wh*7, ww = x / 7, tw = x - ww*7;
  return (wd*64 + wh*8 + ww)*LL + td*49 + th*7 + tw;
}

// LayerNorm over C=128 (f32 src), bf16 out. One wave per row.
__global__ __launch_bounds__(256) void ln_kernel(
    const float* __restrict__ xf, const float* __restrict__ g,
    const float* __restrict__ b, u16* __restrict__ out, int do_map, int shifted)
{
  int wave = threadIdx.x >> 6, lane = threadIdx.x & 63;
  int r = blockIdx.x*4 + wave;
  int pos = do_map ? row_to_pos(r, shifted) : r;
  long src = (long)pos * CC;
  float v0 = xf[src+lane], v1 = xf[src+64+lane];
  float s = v0+v1, ss = v0*v0 + v1*v1;
  #pragma unroll
  for (int o=32; o>0; o>>=1){ s += __shfl_xor(s,o); ss += __shfl_xor(ss,o); }
  float mean = s*(1.f/CC);
  float var  = ss*(1.f/CC) - mean*mean;
  float rstd = rsqrtf(var + 1e-5f);
  long dst = (long)r*CC;
  out[dst + lane]      = f2b((v0-mean)*rstd*g[lane]    + b[lane]);
  out[dst + 64 + lane] = f2b((v1-mean)*rstd*g[64+lane] + b[64+lane]);
}

// All 8 weight transposes (2 blocks x {qkv,proj,fc1,fc2}) in one launch.
__global__ __launch_bounds__(256) void wtall_kernel(
    const float* __restrict__ qkvw, const float* __restrict__ projw,
    const float* __restrict__ fc1w, const float* __restrict__ fc2w,
    u16* __restrict__ wts)
{
  int t = blockIdx.x*256 + threadIdx.x;               // 0..393215
  int blk = t / 196608, r = t - blk*196608;
  const float* in; int Kd, Nd, off;
  if (r < 49152)      { in = qkvw + (size_t)blk*49152; Kd = 128; Nd = 384; off = r; }
  else if (r < 65536) { in = projw + (size_t)blk*16384; Kd = 128; Nd = 128; off = r - 49152; }
  else if (r < 131072){ in = fc1w + (size_t)blk*65536;  Kd = 128; Nd = 512; off = r - 65536; }
  else                { in = fc2w + (size_t)blk*65536;  Kd = 512; Nd = 128; off = r - 131072; }
  int n = off / Kd, k = off - n*Kd;
  wts[t] = f2b(in[k*Nd + n]);
}

// Packed bias(+mask) table in exp2 domain, layout [cls][h][s][i][jj]:
// u32 = (bf16 v(j=s*32+jj, i), bf16 v(j+16, i)).
// v = (rpb-bias - 100*maskneq(cls)) * log2e;  j>=392 -> -1e30.
__global__ __launch_bounds__(256) void biasm_kernel(
    const float* __restrict__ rpb, u32* __restrict__ bm, int total)
{
  int t = blockIdx.x*256 + threadIdx.x;
  if (t >= total) return;
  int jj = t & 15; int rest = t >> 4;
  int i  = rest % 392; rest /= 392;
  int s  = rest % 13;  rest /= 13;
  int h  = rest & 3;   int cls = rest >> 2;
  int tdi=i/49, rmi=i-tdi*49, thi=rmi/7, twi=rmi-thi*7;
  u32 pack = 0;
  #pragma unroll
  for (int half=0; half<2; half++){
    int j = s*32 + jj + half*16;
    float v = -1e30f;
    if (j < LL){
      int tdj=j/49, rmj=j-tdj*49, thj=rmj/7, twj=rmj-thj*7;
      int idx = (tdi-tdj)*169 + (thi-thj)*13 + (twi-twj) + 1267;
      v = rpb[idx*NHEAD + h];
      bool neq = ((cls&4) && ((tdi<4) != (tdj<4)))
              || ((cls&2) && ((thi<4) != (thj<4)))
              || ((cls&1) && ((twi<4) != (twj<4)));
      if (neq) v -= 100.f;
      v *= LOG2E;
    }
    pack |= ((u32)f2b(v)) << (16*half);
  }
  bm[t] = pack;
}

// MFMA GEMM, m97-style staging: C[128x128] = A[rows x KD](bf16) @ Wt^T.
// EPI: 0 = qkv packed epilogue (y0: Q*(scale)+b -> [row][128];
//          y1: K+b -> packed swizzled tiles; y2: V+b -> V^T tiles)
//      1 = +bias, GELU -> bf16 | 2 = +bias, scatter, +Res -> f32 | 3 = accum f32
// LNF: 0 = none | 1 = (EPI2) fuse LN -> OutB at scattered pos
//      2 = (EPI3) fuse LN -> OutB at shifted-window-gathered row
template<int KD, int EPI, int LNF>
__global__ __launch_bounds__(256) void mm_kernel(
    const u16* __restrict__ A, const u16* __restrict__ Wt, int ldw,
    const float* __restrict__ bias, u16* __restrict__ OutB, int ldo,
    float* __restrict__ OutF, const float* __restrict__ Res,
    const float* __restrict__ lng, const float* __restrict__ lnb,
    float scaleq, int shifted, int use_bias)
{
  __shared__ __align__(16) u16 As[128*32];
  __shared__ __align__(16) u16 Bs[128*32];
  const int tid = threadIdx.x, lane = tid & 63, wv = tid >> 6;
  const int quad = lane >> 4, l15 = lane & 15;
  const int rh = wv >> 1, ch = wv & 1;
  const int r0 = blockIdx.x * 128, n0 = blockIdx.y * 128;
  const int srow = lane >> 2, spart = (lane & 3) * 8;  // staging: 16 rows/issue

  f32x4 acc[4][4] = {};

  for (int kt = 0; kt < KD/32; kt++){
    const int k0 = kt*32;
    #pragma unroll
    for (int t=0;t<2;t++){
      const int rowbase = wv*32 + t*16;
      GLDS(&A [(long)(r0 + rowbase + srow)*KD  + k0 + spart], &As[rowbase*32]);
      GLDS(&Wt[(long)(n0 + rowbase + srow)*ldw + k0 + spart], &Bs[rowbase*32]);
    }
    __syncthreads();
    short8 af[4], bf[4];
    #pragma unroll
    for (int rt=0;rt<4;rt++)
      af[rt] = *reinterpret_cast<const short8*>(&As[(rh*64 + rt*16 + l15)*32 + quad*8]);
    #pragma unroll
    for (int ct=0;ct<4;ct++)
      bf[ct] = *reinterpret_cast<const short8*>(&Bs[(ch*64 + ct*16 + l15)*32 + quad*8]);
    #pragma unroll
    for (int rt=0;rt<4;rt++)
      #pragma unroll
      for (int ct=0;ct<4;ct++)
        acc[rt][ct] = __builtin_amdgcn_mfma_f32_16x16x32_bf16(af[rt], bf[ct], acc[rt][ct], 0,0,0);
    __syncthreads();
  }

  if (EPI == 0){
    const int y = blockIdx.y;
    if (y == 0){
      #pragma unroll
      for (int rt=0;rt<4;rt++)
        #pragma unroll
        for (int rr=0;rr<4;rr++){
          const int row_g = r0 + rh*64 + rt*16 + quad*4 + rr;
          #pragma unroll
          for (int ct=0;ct<4;ct++){
            const int c = ch*64 + ct*16 + l15;
            float v = (acc[rt][ct][rr] + bias[c]) * scaleq;
            OutB[(long)row_g*128 + c] = f2b(v);
          }
        }
    } else if (y == 1){
      u16* Kreg = OutB + (size_t)NTOK*128;
      #pragma unroll
      for (int rt=0;rt<4;rt++)
        #pragma unroll
        for (int rr=0;rr<4;rr++){
          const int row_g = r0 + rh*64 + rt*16 + quad*4 + rr;
          const int wi = row_g / 392, key = row_g - wi*392;
          #pragma unroll
          for (int ct=0;ct<4;ct++){
            const int c = ch*64 + ct*16 + l15;
            const int hd = c >> 5, d = c & 31;
            float v = acc[rt][ct][rr] + bias[128 + c];
            Kreg[(size_t)(wi*4 + hd)*KTILE + KADDR(key, d>>3) + (d&7)] = f2b(v);
          }
        }
    } else {
      u16* Vreg = OutB + (size_t)NTOK*256;
      #pragma unroll
      for (int rt=0;rt<4;rt++){
        const int rbase = r0 + rh*64 + rt*16 + quad*4;    // 4-aligned; 392%4==0
        const int wi = rbase / 392, key0 = rbase - wi*392; // -> never crosses w
        #pragma unroll
        for (int ct=0;ct<4;ct++){
          const int c = ch*64 + ct*16 + l15;
          const int hd = c >> 5, d = c & 31;
          const float bb = bias[256 + c];
          u32 lo = cvtpk(acc[rt][ct][0] + bb, acc[rt][ct][1] + bb);
          u32 hi = cvtpk(acc[rt][ct][2] + bb, acc[rt][ct][3] + bb);
          u64 pk = (u64)lo | ((u64)hi << 32);
          *reinterpret_cast<u64*>(&Vreg[(size_t)(wi*4 + hd)*KTILE + (size_t)d*392 + key0]) = pk;
        }
      }
    }
  } else if (LNF == 0){
    #pragma unroll
    for (int rt=0;rt<4;rt++){
      #pragma unroll
      for (int rr=0;rr<4;rr++){
        const int row_g = r0 + rh*64 + rt*16 + quad*4 + rr;
        long pos = 0;
        if (EPI == 2) pos = (long)row_to_pos(row_g, shifted) * CC;
        #pragma unroll
        for (int ct=0;ct<4;ct++){
          const int col_g = n0 + ch*64 + ct*16 + l15;
          float v = acc[rt][ct][rr];
          if (EPI == 1){
            v += bias[col_g];
            v = 0.5f*v*(1.f + erff(v*0.70710678118654752f));
            OutB[(long)row_g*ldo + col_g] = f2b(v);
          } else if (EPI == 2){
            OutF[pos + col_g] = Res[pos + col_g] + v + bias[col_g];
          } else {
            float o = OutF[(long)row_g*CC + col_g] + v;
            if (use_bias) o += bias[col_g];
            OutF[(long)row_g*CC + col_g] = o;
          }
        }
      }
    }
  } else {
    // fused LayerNorm epilogue (requires full 128-col rows: gridDim.y == 1).
    float* red = (float*)As;     // [128 rows][2 ch][2 stats] = 2KB, reuse As
    int pose[4][4];
    #pragma unroll
    for (int rt=0;rt<4;rt++){
      #pragma unroll
      for (int rr=0;rr<4;rr++){
        const int row_g = r0 + rh*64 + rt*16 + quad*4 + rr;
        int pos = (EPI == 2) ? row_to_pos(row_g, shifted) : row_g;
        pose[rt][rr] = pos;
        long pb = (long)pos * CC;
        float s = 0.f, ss = 0.f;
        #pragma unroll
        for (int ct=0;ct<4;ct++){
          const int col_g = n0 + ch*64 + ct*16 + l15;
          float v = acc[rt][ct][rr];
          float o;
          if (EPI == 2) o = Res[pb + col_g] + v + bias[col_g];
          else { o = OutF[pb + col_g] + v; if (use_bias) o += bias[col_g]; }
          OutF[pb + col_g] = o;
          acc[rt][ct][rr] = o;
          s += o; ss += o*o;
        }
        #pragma unroll
        for (int off=1; off<16; off<<=1){
          s  += __shfl_xor(s,  off);
          ss += __shfl_xor(ss, off);
        }
        if (l15 == 0){
          int rl = rh*64 + rt*16 + quad*4 + rr;
          red[rl*4 + ch*2]     = s;
          red[rl*4 + ch*2 + 1] = ss;
        }
      }
    }
    __syncthreads();
    #pragma unroll
    for (int rt=0;rt<4;rt++){
      #pragma unroll
      for (int rr=0;rr<4;rr++){
        const int rl = rh*64 + rt*16 + quad*4 + rr;
        float st  = red[rl*4]     + red[rl*4 + 2];
        float sst = red[rl*4 + 1] + red[rl*4 + 3];
        float mean = st*(1.f/128.f);
        float var  = sst*(1.f/128.f) - mean*mean;
        float rstd = rsqrtf(var + 1e-5f);
        long oidx;
        if (LNF == 1) oidx = (long)pose[rt][rr] * CC;            // linear-pos out
        else          oidx = (long)pos_to_row_sh(pose[rt][rr]) * CC; // window out
        #pragma unroll
        for (int ct=0;ct<4;ct++){
          const int col_g = n0 + ch*64 + ct*16 + l15;
          float val = (acc[rt][ct][rr] - mean)*rstd*lng[col_g] + lnb[col_g];
          OutB[oidx + col_g] = f2b(val);
        }
      }
    }
  }
}

// MFMA flash attention, S^T orientation. One block per (window, head); 8 waves
// x 16-row q-tiles (qt += 8). K/V^T staged via linear global_load_lds from the
// packed tiles the qkv GEMM emitted. 64-key softmax groups; defer-max check on
// UNreduced per-lane max (cross-lane reduce only in the rare rescale branch);
// per-lane partial denominator, reduced once per q-tile. exp2 domain.
__global__ __launch_bounds__(512, 4) void attn_kernel(
    const u16* __restrict__ qkv, const u32* __restrict__ bm,
    u16* __restrict__ out, int shifted)
{
  __shared__ __align__(16) u16 lds[LDS_U16];

  const int w = blockIdx.x >> 2, head = blockIdx.x & 3;
  const int tid = threadIdx.x, lane = tid & 63, wave = tid >> 6;
  const int quad = lane >> 4, l15 = lane & 15;
  const int wd = w>>6, wh = (w>>3)&7, ww = w&7;
  const int cls = shifted ? (((wd!=0)?4:0) | ((wh==7)?2:0) | ((ww==7)?1:0)) : 0;
  const u32* __restrict__ bmh = bm + (size_t)(cls*NHEAD + head)*BM_PER_HEAD;
  const int pbase = POFF + wave*1024;
  const int swz = l15 & 7;
  const int prow = pbase + l15*64;
  const int q2 = quad >> 1, qh = (quad & 1) << 2;

  // stage K tile (25088B) and V^T tile (25088B), both linear
  {
    const u16* Kg = qkv + (size_t)NTOK*128 + (size_t)(w*4+head)*KTILE;
    const u16* Vg = qkv + (size_t)NTOK*256 + (size_t)(w*4+head)*KTILE;
    #pragma unroll
    for (int n = 0; n < 3; n++){
      GLDS(Kg + n*4096 + wave*512 + (lane<<3), &lds[KOFF + n*4096 + wave*512]);
      GLDS(Vg + n*4096 + wave*512 + (lane<<3), &lds[VOFF + n*4096 + wave*512]);
    }
    if (tid < 32){
      GLDS(Kg + 12288 + (lane<<3), &lds[KOFF + 12288]);
      GLDS(Vg + 12288 + (lane<<3), &lds[VOFF + 12288]);
    }
  }
  __syncthreads();

  for (int qt = wave; qt < 25; qt += 8){
    int iq = qt*16 + l15; if (iq > LL-1) iq = LL-1;
    short8 qf = *reinterpret_cast<const short8*>(
        &qkv[((size_t)(w*LL + iq))*128 + head*HDIM + quad*8]);

    float m_s = -1e30f, ls = 0.f;
    f32x4 oc0 = {0.f,0.f,0.f,0.f}, oc1 = {0.f,0.f,0.f,0.f};

    const int bmrow = iq*16 + quad*4;
    u32x4 bmA = *reinterpret_cast<const u32x4*>(&bmh[bmrow]);            // s=0
    u32x4 bmB = *reinterpret_cast<const u32x4*>(&bmh[392*16 + bmrow]);   // s=1
    short8 kf0 = *reinterpret_cast<const short8*>(&lds[KOFF + KADDR(     l15, quad)]);
    short8 kf1 = *reinterpret_cast<const short8*>(&lds[KOFF + KADDR(16 + l15, quad)]);
    short8 kf2 = *reinterpret_cast<const short8*>(&lds[KOFF + KADDR(32 + l15, quad)]);
    short8 kf3 = *reinterpret_cast<const short8*>(&lds[KOFF + KADDR(48 + l15, quad)]);

    for (int it = 0; it < 6; it++){
      const int kb = it*64;
      // prefetch next 64-key group (or the clamped 32-key tail when it==5)
      u32x4 bmAn = {}, bmBn = {};
      short8 kn0 = {}, kn1 = {}, kn2 = {}, kn3 = {};
      if (it < 5){
        bmAn = *reinterpret_cast<const u32x4*>(&bmh[(2*it+2)*392*16 + bmrow]);
        bmBn = *reinterpret_cast<const u32x4*>(&bmh[(2*it+3)*392*16 + bmrow]);
        kn0 = *reinterpret_cast<const short8*>(&lds[KOFF + KADDR(kb + 64 + l15, quad)]);
        kn1 = *reinterpret_cast<const short8*>(&lds[KOFF + KADDR(kb + 80 + l15, quad)]);
        kn2 = *reinterpret_cast<const short8*>(&lds[KOFF + KADDR(kb + 96 + l15, quad)]);
        kn3 = *reinterpret_cast<const short8*>(&lds[KOFF + KADDR(kb +112 + l15, quad)]);
      } else {
        bmAn = *reinterpret_cast<const u32x4*>(&bmh[12*392*16 + bmrow]);
        // tail K rows clamped to real rows 384..391; bias -1e30 kills keys>=392
        kn0 = *reinterpret_cast<const short8*>(&lds[KOFF + KADDR(384 + (l15 & 7), quad)]);
        kn1 = kn0;
      }

      f32x4 z = {0.f,0.f,0.f,0.f};
      __builtin_amdgcn_s_setprio(1);
      f32x4 c0 = __builtin_amdgcn_mfma_f32_16x16x32_bf16(kf0, qf, z, 0,0,0);
      f32x4 c1 = __builtin_amdgcn_mfma_f32_16x16x32_bf16(kf1, qf, z, 0,0,0);
      f32x4 c2 = __builtin_amdgcn_mfma_f32_16x16x32_bf16(kf2, qf, z, 0,0,0);
      f32x4 c3 = __builtin_amdgcn_mfma_f32_16x16x32_bf16(kf3, qf, z, 0,0,0);
      __builtin_amdgcn_s_setprio(0);
      // c0[r]: S[key=kb+quad*4+r][q=iq]; c1: +16; c2: +32; c3: +48 (log2 dom.)

      float s0[4], s1[4], s2[4], s3[4];
      float mt = -1e30f;
      #pragma unroll
      for (int r=0;r<4;r++){
        s0[r] = c0[r] + b2f_lo(bmA[r]);
        s1[r] = c1[r] + b2f_hi(bmA[r]);
        s2[r] = c2[r] + b2f_lo(bmB[r]);
        s3[r] = c3[r] + b2f_hi(bmB[r]);
        mt = fmaxf(mt, fmaxf(fmaxf(s0[r], s1[r]), fmaxf(s2[r], s3[r])));
      }

      // defer-max on the UNreduced per-lane max; reduce only when triggered
      if (!__all(mt <= m_s + 8.f)){
        mt = fmaxf(mt, __shfl_xor(mt, 16));
        mt = fmaxf(mt, __shfl_xor(mt, 32));
        float mn = fmaxf(m_s, mt);
        float al = exp2f(m_s - mn);
        m_s = mn;
        ls *= al;
        #pragma unroll
        for (int r=0;r<4;r++){
          float alr = __shfl(al, quad*4 + r);
          oc0[r] *= alr; oc1[r] *= alr;
        }
      }

      float p0[4], p1[4], p2[4], p3[4];
      #pragma unroll
      for (int r=0;r<4;r++){
        p0[r] = exp2f(s0[r] - m_s);
        p1[r] = exp2f(s1[r] - m_s);
        p2[r] = exp2f(s2[r] - m_s);
        p3[r] = exp2f(s3[r] - m_s);
        ls += (p0[r] + p1[r]) + (p2[r] + p3[r]);
      }

      // P -> wave-private LDS (16 rows x 8 granules, granule ^= l15&7)
      u32x2 w0, w1, w2, w3;
      w0.x = cvtpk(p0[0], p0[1]); w0.y = cvtpk(p0[2], p0[3]);
      w1.x = cvtpk(p1[0], p1[1]); w1.y = cvtpk(p1[2], p1[3]);
      w2.x = cvtpk(p2[0], p2[1]); w2.y = cvtpk(p2[2], p2[3]);
      w3.x = cvtpk(p3[0], p3[1]); w3.y = cvtpk(p3[2], p3[3]);
      *reinterpret_cast<u32x2*>(&lds[prow + (((0 + q2) ^ swz) << 3) + qh]) = w0;
      *reinterpret_cast<u32x2*>(&lds[prow + (((2 + q2) ^ swz) << 3) + qh]) = w1;
      *reinterpret_cast<u32x2*>(&lds[prow + (((4 + q2) ^ swz) << 3) + qh]) = w2;
      *reinterpret_cast<u32x2*>(&lds[prow + (((6 + q2) ^ swz) << 3) + qh]) = w3;

      short8 pa0 = *reinterpret_cast<const short8*>(&lds[prow + (((quad    ) ^ swz) << 3)]);
      short8 pa1 = *reinterpret_cast<const short8*>(&lds[prow + (((quad + 4) ^ swz) << 3)]);
      short8 vb00 = *reinterpret_cast<const short8*>(&lds[VADDR(     l15, kb      + quad*8)]);
      short8 vb01 = *reinterpret_cast<const short8*>(&lds[VADDR(16 + l15, kb      + quad*8)]);
      short8 vb10 = *reinterpret_cast<const short8*>(&lds[VADDR(     l15, kb + 32 + quad*8)]);
      short8 vb11 = *reinterpret_cast<const short8*>(&lds[VADDR(16 + l15, kb + 32 + quad*8)]);
      __builtin_amdgcn_s_setprio(1);
      oc0 = __builtin_amdgcn_mfma_f32_16x16x32_bf16(pa0, vb00, oc0, 0,0,0);
      oc1 = __builtin_amdgcn_mfma_f32_16x16x32_bf16(pa0, vb01, oc1, 0,0,0);
      oc0 = __builtin_amdgcn_mfma_f32_16x16x32_bf16(pa1, vb10, oc0, 0,0,0);
      oc1 = __builtin_amdgcn_mfma_f32_16x16x32_bf16(pa1, vb11, oc1, 0,0,0);
      __builtin_amdgcn_s_setprio(0);

      bmA = bmAn; bmB = bmBn;
      kf0 = kn0; kf1 = kn1; kf2 = kn2; kf3 = kn3;
    }

    // tail: keys 384..415 (K rows clamped; bias kills keys >= 392)
    {
      f32x4 z = {0.f,0.f,0.f,0.f};
      f32x4 c0 = __builtin_amdgcn_mfma_f32_16x16x32_bf16(kf0, qf, z, 0,0,0);
      f32x4 c1 = __builtin_amdgcn_mfma_f32_16x16x32_bf16(kf1, qf, z, 0,0,0);
      float s0[4], s1[4];
      float mt = -1e30f;
      #pragma unroll
      for (int r=0;r<4;r++){
        s0[r] = c0[r] + b2f_lo(bmA[r]);
        s1[r] = c1[r] + b2f_hi(bmA[r]);
        mt = fmaxf(mt, fmaxf(s0[r], s1[r]));
      }
      if (!__all(mt <= m_s + 8.f)){
        mt = fmaxf(mt, __shfl_xor(mt, 16));
        mt = fmaxf(mt, __shfl_xor(mt, 32));
        float mn = fmaxf(m_s, mt);
        float al = exp2f(m_s - mn);
        m_s = mn;
        ls *= al;
        #pragma unroll
        for (int r=0;r<4;r++){
          float alr = __shfl(al, quad*4 + r);
          oc0[r] *= alr; oc1[r] *= alr;
        }
      }
      float p0[4], p1[4];
      #pragma unroll
      for (int r=0;r<4;r++){
        p0[r] = exp2f(s0[r] - m_s);
        p1[r] = exp2f(s1[r] - m_s);
        ls += p0[r] + p1[r];
      }
      u32x2 w0, w1;
      w0.x = cvtpk(p0[0], p0[1]); w0.y = cvtpk(p0[2], p0[3]);
      w1.x = cvtpk(p1[0], p1[1]); w1.y = cvtpk(p1[2], p1[3]);
      *reinterpret_cast<u32x2*>(&lds[prow + (((0 + q2) ^ swz) << 3) + qh]) = w0;
      *reinterpret_cast<u32x2*>(&lds[prow + (((2 + q2) ^ swz) << 3) + qh]) = w1;
      short8 pa0 = *reinterpret_cast<const short8*>(&lds[prow + ((quad ^ swz) << 3)]);
      // V clamped to keys 384..391 for all k-slots; P==0 for keys >= 392
      short8 vb0 = *reinterpret_cast<const short8*>(&lds[VADDR(     l15, 384)]);
      short8 vb1 = *reinterpret_cast<const short8*>(&lds[VADDR(16 + l15, 384)]);
      oc0 = __builtin_amdgcn_mfma_f32_16x16x32_bf16(pa0, vb0, oc0, 0,0,0);
      oc1 = __builtin_amdgcn_mfma_f32_16x16x32_bf16(pa0, vb1, oc1, 0,0,0);
    }

    // denominator: reduce per-lane partials once per q-tile
    ls += __shfl_xor(ls, 16);
    ls += __shfl_xor(ls, 32);
    float inv = 1.f / ls;
    #pragma unroll
    for (int r=0;r<4;r++){
      float invr = __shfl(inv, quad*4 + r);
      int i = qt*16 + quad*4 + r;
      if (i < LL){
        long o = ((long)(w*LL + i))*CC + head*HDIM;
        out[o + l15]      = f2b(oc0[r]*invr);
        out[o + 16 + l15] = f2b(oc1[r]*invr);
      }
    }
  }
}

extern "C" void kernel_launch(void* const* d_in, const int* in_sizes, int n_in,
                              void* d_out, int out_size, void* d_ws, size_t ws_size,
                              hipStream_t stream)
{
  const float* x     = (const float*)d_in[0];
  const float* ln1g  = (const float*)d_in[1];
  const float* ln1b  = (const float*)d_in[2];
  const float* qkvw  = (const float*)d_in[3];
  const float* qkvb  = (const float*)d_in[4];
  const float* rpb   = (const float*)d_in[5];
  const float* projw = (const float*)d_in[6];
  const float* projb = (const float*)d_in[7];
  const float* ln2g  = (const float*)d_in[8];
  const float* ln2b  = (const float*)d_in[9];
  const float* fc1w  = (const float*)d_in[10];
  const float* fc1b  = (const float*)d_in[11];
  const float* fc2w  = (const float*)d_in[12];
  const float* fc2b  = (const float*)d_in[13];
  float* outf = (float*)d_out;                  // f32 residual stream / output

  u16* buf1 = (u16*)d_ws;                       // bf16 act (window space), NTOK*128
  u16* bufq = buf1 + (size_t)NTOK*CC;           // Q | Kpack | V^T  (NTOK*384 u16)
  u16* ln2o = bufq + (size_t)NTOK*256;          // LN2 output (linear space, post-attn)
  u16* wts  = bufq + (size_t)NTOK*384;          // transposed bf16 weights
  u32* bm   = (u32*)(wts + 393216);             // packed bias+mask table

  // all weight transposes in one launch
  wtall_kernel<<<1536, 256, 0, stream>>>(qkvw, projw, fc1w, fc2w, wts);

  for (int blk = 0; blk < 2; ++blk){
    const int sh = blk;
    const float* resid = (blk==0) ? x : outf;
    u16* wb = wts + (size_t)blk*196608;

    // block 0 (unshifted) only uses mask class 0 -> build 1/8 of the table
    const int bmtot = (blk==0) ? 4*BM_PER_HEAD : BM_TOTAL;
    biasm_kernel<<<(bmtot+255)/256, 256, 0, stream>>>(
        rpb + (size_t)blk*2535*NHEAD, bm, bmtot);
    // LN1 + roll + window gather: separate kernel only for block 0 (from x);
    // block 1's LN1 is fused into block 0's fc2-h1 epilogue.
    if (blk == 0)
      ln_kernel<<<NTOK/4, 256, 0, stream>>>(resid,
          ln1g, ln1b, buf1, 1, 0);
    // QKV GEMM -> packed attention tiles (q pre-scaled by 32^-0.5 * log2e)
    mm_kernel<128,0,0><<<dim3(392,3), 256, 0, stream>>>(
        buf1, wb, 128, qkvb + blk*384, bufq, 128,
        nullptr, nullptr, nullptr, nullptr, QKSCALE*LOG2E, 0, 0);
    // attention (128 windows x 4 heads), 8 waves/block
    attn_kernel<<<NWIN*NHEAD, 512, 0, stream>>>(bufq, bm, buf1, sh);
    // proj + reverse/roll-back scatter + residual -> outf; fused LN2 -> ln2o
    mm_kernel<128,2,1><<<dim3(392,1), 256, 0, stream>>>(
        buf1, wb+49152, 128, projb + blk*CC, ln2o, 0,
        outf, resid, ln2g + blk*CC, ln2b + blk*CC, 1.f, sh, 0);
    // MLP in 2 column-halves of 256 (hidden reuses bufq rows x 256)
    for (int h = 0; h < 2; ++h){
      mm_kernel<128,1,0><<<dim3(392,2), 256, 0, stream>>>(
          ln2o, wb + 65536 + (size_t)h*256*128, 128,
          fc1b + blk*512 + h*256, bufq, 256,
          nullptr, nullptr, nullptr, nullptr, 1.f, 0, 0);
      if (h == 0){
        mm_kernel<256,3,0><<<dim3(392,1), 256, 0, stream>>>(
            bufq, wb + 131072, 512,
            fc2b + blk*CC, nullptr, 0,
            outf, nullptr, nullptr, nullptr, 1.f, 0, 1);
      } else if (blk == 0){
        // final fc2 half of block 0: fuse LN1(+shifted window gather) for blk1
        mm_kernel<256,3,2><<<dim3(392,1), 256, 0, stream>>>(
            bufq, wb + 131072 + 256, 512,
            fc2b, buf1, 0,
            outf, nullptr, ln1g + CC, ln1b + CC, 1.f, 0, 0);
      } else {
        mm_kernel<256,3,0><<<dim3(392,1), 256, 0, stream>>>(
            bufq, wb + 131072 + 256, 512,
            fc2b + CC, nullptr, 0,
            outf, nullptr, nullptr, nullptr, 1.f, 0, 0);
      }
    }
  }
}

// Round 5
// 479.675 us; speedup vs baseline: 1.1662x; 1.0023x over previous
//
#include <hip/hip_runtime.h>
#include <hip/hip_bf16.h>
#include <math.h>

// VideoSwinBasicLayer: 2 swin blocks (W-MSA, SW-MSA) on (1,16,56,56,128), NH=4,
// window (8,7,7) -> L=392, nW=128, shift (4,3,3), HID=512. IO f32.
// R12: attn exp2-direct softmax (no max tracking: logits structurally bounded,
// mask bias -144 -> exp2 -> exact 0) -> shorter VALU chain, no cross-group
// serialization. mm_kernel restructured: single-stage BK=128 (64KB LDS, XOR
// swizzle baked into global_load_lds source), ONE barrier per tile instead of 8.
// ws unchanged: buf1 12.85MB | bufq 38.5MB | wtsT 0.79MB | bm 10.44MB = 62.6MB.

#define NTOK 50176   // 16*56*56
#define CC   128
#define LL   392
#define NWIN 128
#define NHEAD 4
#define HDIM 32
#define QKSCALE 0.17677669529663687f  // 32^-0.5
#define LOG2E   1.4426950408889634f

// attention LDS layout (u16 units)
#define KOFF    0             // K: 392 rows x 32 (granule-swizzled) = 12544 u16
#define VOFF    12544         // V^T: 32 x 392 = 12544 u16
#define POFF    25088         // P: 8 waves x 1024 (16 q-rows x 128B, swizzled)
#define LDS_U16 33280         // 66560 B -> 2 blocks/CU

#define KTILE   12544         // u16 per (w,head) K or V tile

// K tile: row-major [row][32], b128 granule g (0..3) swizzled by row bits 0..3.
// Same formula on the global-write side (mm epilogue) and LDS-read side.
#define KADDR(row, g) (((row) << 5) + ((((g) ^ ((row) & 3) ^ (((row) >> 2) & 3))) << 3))
// V^T tile: [d][392] u16, linear. stride 392 u16 = 196 dw = 4 mod 32 -> 2-way max.
#define VADDR(d, k) (VOFF + (d)*392 + (k))

#define BM_PER_HEAD (13*392*16)            // u32 per (cls,head) slice
#define BM_TOTAL    (8*4*BM_PER_HEAD)      // 10.44 MB

typedef unsigned short u16;
typedef unsigned int   u32;
typedef unsigned long long u64;
typedef __attribute__((ext_vector_type(8))) short short8;
typedef __attribute__((ext_vector_type(4))) float f32x4;
typedef __attribute__((ext_vector_type(2))) unsigned int u32x2;
typedef __attribute__((ext_vector_type(4))) unsigned int u32x4;

// async global->LDS, 16B per lane; LDS dest = wave-uniform base + lane*16.
#define GLDS(gp, lp) __builtin_amdgcn_global_load_lds( \
    (const __attribute__((address_space(1))) void*)(gp), \
    (__attribute__((address_space(3))) void*)(lp), 16, 0, 0)

__device__ __forceinline__ float b2f_lo(u32 u){ return __uint_as_float(u<<16); }
__device__ __forceinline__ float b2f_hi(u32 u){ return __uint_as_float(u & 0xffff0000u); }
__device__ __forceinline__ u16 f2b(float f){
  __hip_bfloat16 h = __float2bfloat16(f);
  return *reinterpret_cast<u16*>(&h);
}
// pack 2 f32 -> 2 bf16 (RNE) in one instruction; lo->bits[15:0], hi->bits[31:16]
__device__ __forceinline__ u32 cvtpk(float lo, float hi){
  u32 r; asm("v_cvt_pk_bf16_f32 %0, %1, %2" : "=v"(r) : "v"(lo), "v"(hi)); return r;
}

// window-ordered row r -> flat token position (roll(+shift) both directions).
__device__ __forceinline__ int row_to_pos(int r, int shifted){
  int w = r / LL, t = r - w*LL;
  int wd = w >> 6, wh = (w >> 3) & 7, ww = w & 7;
  int td = t / 49, rem = t - td*49, th = rem / 7, tw = rem - th*7;
  int d = wd*8 + td, h = wh*7 + th, x = ww*7 + tw;
  if (shifted){ d = (d+4)&15; h += 3; if (h>=56) h-=56; x += 3; if (x>=56) x-=56; }
  return (d*56 + h)*56 + x;
}

// inverse of row_to_pos with shifted=1: flat token position -> window row.
__device__ __forceinline__ int pos_to_row_sh(int p){
  int d = p / 3136, rem = p - d*3136, h = rem / 56, x = rem - h*56;
  d = (d + 12) & 15; h -= 3; if (h < 0) h += 56; x -= 3; if (x < 0) x += 56;
  int wd = d >> 3, td = d & 7;
  int wh = h / 7, th = h - wh*7, ww = x / 7, tw = x - ww*7;
  return (wd*64 + wh*8 + ww)*LL + td*49 + th*7 + tw;
}

// LayerNorm over C=128 (f32 src), bf16 out. One wave per row.
__global__ __launch_bounds__(256) void ln_kernel(
    const float* __restrict__ xf, const float* __restrict__ g,
    const float* __restrict__ b, u16* __restrict__ out, int do_map, int shifted)
{
  int wave = threadIdx.x >> 6, lane = threadIdx.x & 63;
  int r = blockIdx.x*4 + wave;
  int pos = do_map ? row_to_pos(r, shifted) : r;
  long src = (long)pos * CC;
  float v0 = xf[src+lane], v1 = xf[src+64+lane];
  float s = v0+v1, ss = v0*v0 + v1*v1;
  #pragma unroll
  for (int o=32; o>0; o>>=1){ s += __shfl_xor(s,o); ss += __shfl_xor(ss,o); }
  float mean = s*(1.f/CC);
  float var  = ss*(1.f/CC) - mean*mean;
  float rstd = rsqrtf(var + 1e-5f);
  long dst = (long)r*CC;
  out[dst + lane]      = f2b((v0-mean)*rstd*g[lane]    + b[lane]);
  out[dst + 64 + lane] = f2b((v1-mean)*rstd*g[64+lane] + b[64+lane]);
}

// All 8 weight transposes (2 blocks x {qkv,proj,fc1,fc2}) in one launch.
__global__ __launch_bounds__(256) void wtall_kernel(
    const float* __restrict__ qkvw, const float* __restrict__ projw,
    const float* __restrict__ fc1w, const float* __restrict__ fc2w,
    u16* __restrict__ wts)
{
  int t = blockIdx.x*256 + threadIdx.x;               // 0..393215
  int blk = t / 196608, r = t - blk*196608;
  const float* in; int Kd, Nd, off;
  if (r < 49152)      { in = qkvw + (size_t)blk*49152; Kd = 128; Nd = 384; off = r; }
  else if (r < 65536) { in = projw + (size_t)blk*16384; Kd = 128; Nd = 128; off = r - 49152; }
  else if (r < 131072){ in = fc1w + (size_t)blk*65536;  Kd = 128; Nd = 512; off = r - 65536; }
  else                { in = fc2w + (size_t)blk*65536;  Kd = 512; Nd = 128; off = r - 131072; }
  int n = off / Kd, k = off - n*Kd;
  wts[t] = f2b(in[k*Nd + n]);
}

// Packed bias(+mask) table in exp2 domain, layout [cls][h][s][i][jj]:
// u32 = (bf16 v(j=s*32+jj, i), bf16 v(j+16, i)).
// v = (rpb-bias - 100*maskneq(cls)) * log2e;  j>=392 -> -1e30.
__global__ __launch_bounds__(256) void biasm_kernel(
    const float* __restrict__ rpb, u32* __restrict__ bm, int total)
{
  int t = blockIdx.x*256 + threadIdx.x;
  if (t >= total) return;
  int jj = t & 15; int rest = t >> 4;
  int i  = rest % 392; rest /= 392;
  int s  = rest % 13;  rest /= 13;
  int h  = rest & 3;   int cls = rest >> 2;
  int tdi=i/49, rmi=i-tdi*49, thi=rmi/7, twi=rmi-thi*7;
  u32 pack = 0;
  #pragma unroll
  for (int half=0; half<2; half++){
    int j = s*32 + jj + half*16;
    float v = -1e30f;
    if (j < LL){
      int tdj=j/49, rmj=j-tdj*49, thj=rmj/7, twj=rmj-thj*7;
      int idx = (tdi-tdj)*169 + (thi-thj)*13 + (twi-twj) + 1267;
      v = rpb[idx*NHEAD + h];
      bool neq = ((cls&4) && ((tdi<4) != (tdj<4)))
              || ((cls&2) && ((thi<4) != (thj<4)))
              || ((cls&1) && ((twi<4) != (twj<4)));
      if (neq) v -= 100.f;
      v *= LOG2E;
    }
    pack |= ((u32)f2b(v)) << (16*half);
  }
  bm[t] = pack;
}

// MFMA GEMM, single-stage: whole A[128][128] and W[128][128] K-panel staged
// once (64KB LDS, XOR granule swizzle baked into the global_load_lds source),
// ONE barrier, then 64 MFMA + 32 ds_read_b128 with no further syncs.
// KD=256 runs 2 chunks (3 barriers).
// EPI: 0 = qkv packed epilogue (y0: Q*(scale)+b -> [row][128];
//          y1: K+b -> packed swizzled tiles; y2: V+b -> V^T tiles)
//      1 = +bias, GELU -> bf16 | 2 = +bias, scatter, +Res -> f32 | 3 = accum f32
// LNF: 0 = none | 1 = (EPI2) fuse LN -> OutB at scattered pos
//      2 = (EPI3) fuse LN -> OutB at shifted-window-gathered row
template<int KD, int EPI, int LNF>
__global__ __launch_bounds__(256) void mm_kernel(
    const u16* __restrict__ A, const u16* __restrict__ Wt, int ldw,
    const float* __restrict__ bias, u16* __restrict__ OutB, int ldo,
    float* __restrict__ OutF, const float* __restrict__ Res,
    const float* __restrict__ lng, const float* __restrict__ lnb,
    float scaleq, int shifted, int use_bias)
{
  __shared__ __align__(16) u16 As[128*128];   // 32KB
  __shared__ __align__(16) u16 Bs[128*128];   // 32KB
  const int tid = threadIdx.x, lane = tid & 63, wv = tid >> 6;
  const int quad = lane >> 4, l15 = lane & 15;
  const int rh = wv >> 1, ch = wv & 1;
  const int r0 = blockIdx.x * 128, n0 = blockIdx.y * 128;
  const int srow_off = lane >> 4;        // row within 4-row issue
  const int sgran = lane & 15;           // phys 16B granule within row

  f32x4 acc[4][4] = {};

  for (int kc = 0; kc < KD/128; kc++){
    const int k0 = kc*128;
    if (kc > 0) __syncthreads();         // all waves done reading before restage
    #pragma unroll
    for (int i=0;i<8;i++){
      const int gi = wv*8 + i;           // 0..31, 4 rows per issue
      const int row = gi*4 + srow_off;
      const int sw = row & 7;
      GLDS(&A [(long)(r0 + row)*KD  + k0 + ((sgran ^ sw)<<3)], &As[gi*512]);
      GLDS(&Wt[(long)(n0 + row)*ldw + k0 + ((sgran ^ sw)<<3)], &Bs[gi*512]);
    }
    __syncthreads();
    #pragma unroll
    for (int ks=0;ks<4;ks++){
      short8 af[4], bf[4];
      #pragma unroll
      for (int rt=0;rt<4;rt++){
        const int row = rh*64 + rt*16 + l15;
        af[rt] = *reinterpret_cast<const short8*>(
            &As[row*128 + (((ks*4+quad) ^ (l15&7))<<3)]);
      }
      #pragma unroll
      for (int ct=0;ct<4;ct++){
        const int row = ch*64 + ct*16 + l15;
        bf[ct] = *reinterpret_cast<const short8*>(
            &Bs[row*128 + (((ks*4+quad) ^ (l15&7))<<3)]);
      }
      #pragma unroll
      for (int rt=0;rt<4;rt++)
        #pragma unroll
        for (int ct=0;ct<4;ct++)
          acc[rt][ct] = __builtin_amdgcn_mfma_f32_16x16x32_bf16(af[rt], bf[ct], acc[rt][ct], 0,0,0);
    }
  }

  if (EPI == 0){
    const int y = blockIdx.y;
    if (y == 0){
      #pragma unroll
      for (int rt=0;rt<4;rt++)
        #pragma unroll
        for (int rr=0;rr<4;rr++){
          const int row_g = r0 + rh*64 + rt*16 + quad*4 + rr;
          #pragma unroll
          for (int ct=0;ct<4;ct++){
            const int c = ch*64 + ct*16 + l15;
            float v = (acc[rt][ct][rr] + bias[c]) * scaleq;
            OutB[(long)row_g*128 + c] = f2b(v);
          }
        }
    } else if (y == 1){
      u16* Kreg = OutB + (size_t)NTOK*128;
      #pragma unroll
      for (int rt=0;rt<4;rt++)
        #pragma unroll
        for (int rr=0;rr<4;rr++){
          const int row_g = r0 + rh*64 + rt*16 + quad*4 + rr;
          const int wi = row_g / 392, key = row_g - wi*392;
          #pragma unroll
          for (int ct=0;ct<4;ct++){
            const int c = ch*64 + ct*16 + l15;
            const int hd = c >> 5, d = c & 31;
            float v = acc[rt][ct][rr] + bias[128 + c];
            Kreg[(size_t)(wi*4 + hd)*KTILE + KADDR(key, d>>3) + (d&7)] = f2b(v);
          }
        }
    } else {
      u16* Vreg = OutB + (size_t)NTOK*256;
      #pragma unroll
      for (int rt=0;rt<4;rt++){
        const int rbase = r0 + rh*64 + rt*16 + quad*4;    // 4-aligned; 392%4==0
        const int wi = rbase / 392, key0 = rbase - wi*392; // -> never crosses w
        #pragma unroll
        for (int ct=0;ct<4;ct++){
          const int c = ch*64 + ct*16 + l15;
          const int hd = c >> 5, d = c & 31;
          const float bb = bias[256 + c];
          u32 lo = cvtpk(acc[rt][ct][0] + bb, acc[rt][ct][1] + bb);
          u32 hi = cvtpk(acc[rt][ct][2] + bb, acc[rt][ct][3] + bb);
          u64 pk = (u64)lo | ((u64)hi << 32);
          *reinterpret_cast<u64*>(&Vreg[(size_t)(wi*4 + hd)*KTILE + (size_t)d*392 + key0]) = pk;
        }
      }
    }
  } else if (LNF == 0){
    #pragma unroll
    for (int rt=0;rt<4;rt++){
      #pragma unroll
      for (int rr=0;rr<4;rr++){
        const int row_g = r0 + rh*64 + rt*16 + quad*4 + rr;
        long pos = 0;
        if (EPI == 2) pos = (long)row_to_pos(row_g, shifted) * CC;
        #pragma unroll
        for (int ct=0;ct<4;ct++){
          const int col_g = n0 + ch*64 + ct*16 + l15;
          float v = acc[rt][ct][rr];
          if (EPI == 1){
            v += bias[col_g];
            v = 0.5f*v*(1.f + erff(v*0.70710678118654752f));
            OutB[(long)row_g*ldo + col_g] = f2b(v);
          } else if (EPI == 2){
            OutF[pos + col_g] = Res[pos + col_g] + v + bias[col_g];
          } else {
            float o = OutF[(long)row_g*CC + col_g] + v;
            if (use_bias) o += bias[col_g];
            OutF[(long)row_g*CC + col_g] = o;
          }
        }
      }
    }
  } else {
    // fused LayerNorm epilogue (requires full 128-col rows: gridDim.y == 1).
    __syncthreads();             // all waves done with As before scratch reuse
    float* red = (float*)As;     // [128 rows][2 ch][2 stats] = 2KB, reuse As
    int pose[4][4];
    #pragma unroll
    for (int rt=0;rt<4;rt++){
      #pragma unroll
      for (int rr=0;rr<4;rr++){
        const int row_g = r0 + rh*64 + rt*16 + quad*4 + rr;
        int pos = (EPI == 2) ? row_to_pos(row_g, shifted) : row_g;
        pose[rt][rr] = pos;
        long pb = (long)pos * CC;
        float s = 0.f, ss = 0.f;
        #pragma unroll
        for (int ct=0;ct<4;ct++){
          const int col_g = n0 + ch*64 + ct*16 + l15;
          float v = acc[rt][ct][rr];
          float o;
          if (EPI == 2) o = Res[pb + col_g] + v + bias[col_g];
          else { o = OutF[pb + col_g] + v; if (use_bias) o += bias[col_g]; }
          OutF[pb + col_g] = o;
          acc[rt][ct][rr] = o;
          s += o; ss += o*o;
        }
        #pragma unroll
        for (int off=1; off<16; off<<=1){
          s  += __shfl_xor(s,  off);
          ss += __shfl_xor(ss, off);
        }
        if (l15 == 0){
          int rl = rh*64 + rt*16 + quad*4 + rr;
          red[rl*4 + ch*2]     = s;
          red[rl*4 + ch*2 + 1] = ss;
        }
      }
    }
    __syncthreads();
    #pragma unroll
    for (int rt=0;rt<4;rt++){
      #pragma unroll
      for (int rr=0;rr<4;rr++){
        const int rl = rh*64 + rt*16 + quad*4 + rr;
        float st  = red[rl*4]     + red[rl*4 + 2];
        float sst = red[rl*4 + 1] + red[rl*4 + 3];
        float mean = st*(1.f/128.f);
        float var  = sst*(1.f/128.f) - mean*mean;
        float rstd = rsqrtf(var + 1e-5f);
        long oidx;
        if (LNF == 1) oidx = (long)pose[rt][rr] * CC;            // linear-pos out
        else          oidx = (long)pos_to_row_sh(pose[rt][rr]) * CC; // window out
        #pragma unroll
        for (int ct=0;ct<4;ct++){
          const int col_g = n0 + ch*64 + ct*16 + l15;
          float val = (acc[rt][ct][rr] - mean)*rstd*lng[col_g] + lnb[col_g];
          OutB[oidx + col_g] = f2b(val);
        }
      }
    }
  }
}

// MFMA flash attention, S^T orientation. One block per (window, head); 8 waves
// x 16-row q-tiles (qt += 8). K/V^T staged via linear global_load_lds from the
// packed tiles the qkv GEMM emitted. exp2-DIRECT softmax: no max tracking
// (logits structurally bounded; mask bias -144 -> exp2 -> exact 0), so groups
// have no serial state except the accumulators. Per-lane partial denominator,
// reduced once per q-tile.
__global__ __launch_bounds__(512, 4) void attn_kernel(
    const u16* __restrict__ qkv, const u32* __restrict__ bm,
    u16* __restrict__ out, int shifted)
{
  __shared__ __align__(16) u16 lds[LDS_U16];

  const int w = blockIdx.x >> 2, head = blockIdx.x & 3;
  const int tid = threadIdx.x, lane = tid & 63, wave = tid >> 6;
  const int quad = lane >> 4, l15 = lane & 15;
  const int wd = w>>6, wh = (w>>3)&7, ww = w&7;
  const int cls = shifted ? (((wd!=0)?4:0) | ((wh==7)?2:0) | ((ww==7)?1:0)) : 0;
  const u32* __restrict__ bmh = bm + (size_t)(cls*NHEAD + head)*BM_PER_HEAD;
  const int pbase = POFF + wave*1024;
  const int swz = l15 & 7;
  const int prow = pbase + l15*64;
  const int q2 = quad >> 1, qh = (quad & 1) << 2;

  // stage K tile (25088B) and V^T tile (25088B), both linear
  {
    const u16* Kg = qkv + (size_t)NTOK*128 + (size_t)(w*4+head)*KTILE;
    const u16* Vg = qkv + (size_t)NTOK*256 + (size_t)(w*4+head)*KTILE;
    #pragma unroll
    for (int n = 0; n < 3; n++){
      GLDS(Kg + n*4096 + wave*512 + (lane<<3), &lds[KOFF + n*4096 + wave*512]);
      GLDS(Vg + n*4096 + wave*512 + (lane<<3), &lds[VOFF + n*4096 + wave*512]);
    }
    if (tid < 32){
      GLDS(Kg + 12288 + (lane<<3), &lds[KOFF + 12288]);
      GLDS(Vg + 12288 + (lane<<3), &lds[VOFF + 12288]);
    }
  }
  __syncthreads();

  for (int qt = wave; qt < 25; qt += 8){
    int iq = qt*16 + l15; if (iq > LL-1) iq = LL-1;
    short8 qf = *reinterpret_cast<const short8*>(
        &qkv[((size_t)(w*LL + iq))*128 + head*HDIM + quad*8]);

    float ls = 0.f;
    f32x4 oc0 = {0.f,0.f,0.f,0.f}, oc1 = {0.f,0.f,0.f,0.f};

    const int bmrow = iq*16 + quad*4;
    u32x4 bmA = *reinterpret_cast<const u32x4*>(&bmh[bmrow]);            // s=0
    u32x4 bmB = *reinterpret_cast<const u32x4*>(&bmh[392*16 + bmrow]);   // s=1
    short8 kf0 = *reinterpret_cast<const short8*>(&lds[KOFF + KADDR(     l15, quad)]);
    short8 kf1 = *reinterpret_cast<const short8*>(&lds[KOFF + KADDR(16 + l15, quad)]);
    short8 kf2 = *reinterpret_cast<const short8*>(&lds[KOFF + KADDR(32 + l15, quad)]);
    short8 kf3 = *reinterpret_cast<const short8*>(&lds[KOFF + KADDR(48 + l15, quad)]);

    for (int it = 0; it < 6; it++){
      const int kb = it*64;
      // prefetch next 64-key group (or the clamped 32-key tail when it==5)
      u32x4 bmAn = {}, bmBn = {};
      short8 kn0 = {}, kn1 = {}, kn2 = {}, kn3 = {};
      if (it < 5){
        bmAn = *reinterpret_cast<const u32x4*>(&bmh[(2*it+2)*392*16 + bmrow]);
        bmBn = *reinterpret_cast<const u32x4*>(&bmh[(2*it+3)*392*16 + bmrow]);
        kn0 = *reinterpret_cast<const short8*>(&lds[KOFF + KADDR(kb + 64 + l15, quad)]);
        kn1 = *reinterpret_cast<const short8*>(&lds[KOFF + KADDR(kb + 80 + l15, quad)]);
        kn2 = *reinterpret_cast<const short8*>(&lds[KOFF + KADDR(kb + 96 + l15, quad)]);
        kn3 = *reinterpret_cast<const short8*>(&lds[KOFF + KADDR(kb +112 + l15, quad)]);
      } else {
        bmAn = *reinterpret_cast<const u32x4*>(&bmh[12*392*16 + bmrow]);
        // tail K rows clamped to real rows 384..391; bias -1e30 kills keys>=392
        kn0 = *reinterpret_cast<const short8*>(&lds[KOFF + KADDR(384 + (l15 & 7), quad)]);
        kn1 = kn0;
      }

      f32x4 z = {0.f,0.f,0.f,0.f};
      __builtin_amdgcn_s_setprio(1);
      f32x4 c0 = __builtin_amdgcn_mfma_f32_16x16x32_bf16(kf0, qf, z, 0,0,0);
      f32x4 c1 = __builtin_amdgcn_mfma_f32_16x16x32_bf16(kf1, qf, z, 0,0,0);
      f32x4 c2 = __builtin_amdgcn_mfma_f32_16x16x32_bf16(kf2, qf, z, 0,0,0);
      f32x4 c3 = __builtin_amdgcn_mfma_f32_16x16x32_bf16(kf3, qf, z, 0,0,0);
      __builtin_amdgcn_s_setprio(0);
      // c0[r]: S[key=kb+quad*4+r][q=iq]; c1: +16; c2: +32; c3: +48 (log2 dom.)

      float p0[4], p1[4], p2[4], p3[4];
      #pragma unroll
      for (int r=0;r<4;r++){
        p0[r] = exp2f(c0[r] + b2f_lo(bmA[r]));
        p1[r] = exp2f(c1[r] + b2f_hi(bmA[r]));
        p2[r] = exp2f(c2[r] + b2f_lo(bmB[r]));
        p3[r] = exp2f(c3[r] + b2f_hi(bmB[r]));
        ls += (p0[r] + p1[r]) + (p2[r] + p3[r]);
      }

      // P -> wave-private LDS (16 rows x 8 granules, granule ^= l15&7)
      u32x2 w0, w1, w2, w3;
      w0.x = cvtpk(p0[0], p0[1]); w0.y = cvtpk(p0[2], p0[3]);
      w1.x = cvtpk(p1[0], p1[1]); w1.y = cvtpk(p1[2], p1[3]);
      w2.x = cvtpk(p2[0], p2[1]); w2.y = cvtpk(p2[2], p2[3]);
      w3.x = cvtpk(p3[0], p3[1]); w3.y = cvtpk(p3[2], p3[3]);
      *reinterpret_cast<u32x2*>(&lds[prow + (((0 + q2) ^ swz) << 3) + qh]) = w0;
      *reinterpret_cast<u32x2*>(&lds[prow + (((2 + q2) ^ swz) << 3) + qh]) = w1;
      *reinterpret_cast<u32x2*>(&lds[prow + (((4 + q2) ^ swz) << 3) + qh]) = w2;
      *reinterpret_cast<u32x2*>(&lds[prow + (((6 + q2) ^ swz) << 3) + qh]) = w3;

      short8 pa0 = *reinterpret_cast<const short8*>(&lds[prow + (((quad    ) ^ swz) << 3)]);
      short8 pa1 = *reinterpret_cast<const short8*>(&lds[prow + (((quad + 4) ^ swz) << 3)]);
      short8 vb00 = *reinterpret_cast<const short8*>(&lds[VADDR(     l15, kb      + quad*8)]);
      short8 vb01 = *reinterpret_cast<const short8*>(&lds[VADDR(16 + l15, kb      + quad*8)]);
      short8 vb10 = *reinterpret_cast<const short8*>(&lds[VADDR(     l15, kb + 32 + quad*8)]);
      short8 vb11 = *reinterpret_cast<const short8*>(&lds[VADDR(16 + l15, kb + 32 + quad*8)]);
      __builtin_amdgcn_s_setprio(1);
      oc0 = __builtin_amdgcn_mfma_f32_16x16x32_bf16(pa0, vb00, oc0, 0,0,0);
      oc1 = __builtin_amdgcn_mfma_f32_16x16x32_bf16(pa0, vb01, oc1, 0,0,0);
      oc0 = __builtin_amdgcn_mfma_f32_16x16x32_bf16(pa1, vb10, oc0, 0,0,0);
      oc1 = __builtin_amdgcn_mfma_f32_16x16x32_bf16(pa1, vb11, oc1, 0,0,0);
      __builtin_amdgcn_s_setprio(0);

      bmA = bmAn; bmB = bmBn;
      kf0 = kn0; kf1 = kn1; kf2 = kn2; kf3 = kn3;
    }

    // tail: keys 384..415 (K rows clamped; bias kills keys >= 392)
    {
      f32x4 z = {0.f,0.f,0.f,0.f};
      f32x4 c0 = __builtin_amdgcn_mfma_f32_16x16x32_bf16(kf0, qf, z, 0,0,0);
      f32x4 c1 = __builtin_amdgcn_mfma_f32_16x16x32_bf16(kf1, qf, z, 0,0,0);
      float p0[4], p1[4];
      #pragma unroll
      for (int r=0;r<4;r++){
        p0[r] = exp2f(c0[r] + b2f_lo(bmA[r]));
        p1[r] = exp2f(c1[r] + b2f_hi(bmA[r]));
        ls += p0[r] + p1[r];
      }
      u32x2 w0, w1;
      w0.x = cvtpk(p0[0], p0[1]); w0.y = cvtpk(p0[2], p0[3]);
      w1.x = cvtpk(p1[0], p1[1]); w1.y = cvtpk(p1[2], p1[3]);
      *reinterpret_cast<u32x2*>(&lds[prow + (((0 + q2) ^ swz) << 3) + qh]) = w0;
      *reinterpret_cast<u32x2*>(&lds[prow + (((2 + q2) ^ swz) << 3) + qh]) = w1;
      short8 pa0 = *reinterpret_cast<const short8*>(&lds[prow + ((quad ^ swz) << 3)]);
      // V clamped to keys 384..391 for all k-slots; P==0 for keys >= 392
      short8 vb0 = *reinterpret_cast<const short8*>(&lds[VADDR(     l15, 384)]);
      short8 vb1 = *reinterpret_cast<const short8*>(&lds[VADDR(16 + l15, 384)]);
      oc0 = __builtin_amdgcn_mfma_f32_16x16x32_bf16(pa0, vb0, oc0, 0,0,0);
      oc1 = __builtin_amdgcn_mfma_f32_16x16x32_bf16(pa0, vb1, oc1, 0,0,0);
    }

    // denominator: reduce per-lane partials once per q-tile
    ls += __shfl_xor(ls, 16);
    ls += __shfl_xor(ls, 32);
    float inv = 1.f / ls;
    #pragma unroll
    for (int r=0;r<4;r++){
      float invr = __shfl(inv, quad*4 + r);
      int i = qt*16 + quad*4 + r;
      if (i < LL){
        long o = ((long)(w*LL + i))*CC + head*HDIM;
        out[o + l15]      = f2b(oc0[r]*invr);
        out[o + 16 + l15] = f2b(oc1[r]*invr);
      }
    }
  }
}

extern "C" void kernel_launch(void* const* d_in, const int* in_sizes, int n_in,
                              void* d_out, int out_size, void* d_ws, size_t ws_size,
                              hipStream_t stream)
{
  const float* x     = (const float*)d_in[0];
  const float* ln1g  = (const float*)d_in[1];
  const float* ln1b  = (const float*)d_in[2];
  const float* qkvw  = (const float*)d_in[3];
  const float* qkvb  = (const float*)d_in[4];
  const float* rpb   = (const float*)d_in[5];
  const float* projw = (const float*)d_in[6];
  const float* projb = (const float*)d_in[7];
  const float* ln2g  = (const float*)d_in[8];
  const float* ln2b  = (const float*)d_in[9];
  const float* fc1w  = (const float*)d_in[10];
  const float* fc1b  = (const float*)d_in[11];
  const float* fc2w  = (const float*)d_in[12];
  const float* fc2b  = (const float*)d_in[13];
  float* outf = (float*)d_out;                  // f32 residual stream / output

  u16* buf1 = (u16*)d_ws;                       // bf16 act (window space), NTOK*128
  u16* bufq = buf1 + (size_t)NTOK*CC;           // Q | Kpack | V^T  (NTOK*384 u16)
  u16* ln2o = bufq + (size_t)NTOK*256;          // LN2 output (linear space, post-attn)
  u16* wts  = bufq + (size_t)NTOK*384;          // transposed bf16 weights
  u32* bm   = (u32*)(wts + 393216);             // packed bias+mask table

  // all weight transposes in one launch
  wtall_kernel<<<1536, 256, 0, stream>>>(qkvw, projw, fc1w, fc2w, wts);

  for (int blk = 0; blk < 2; ++blk){
    const int sh = blk;
    const float* resid = (blk==0) ? x : outf;
    u16* wb = wts + (size_t)blk*196608;

    // block 0 (unshifted) only uses mask class 0 -> build 1/8 of the table
    const int bmtot = (blk==0) ? 4*BM_PER_HEAD : BM_TOTAL;
    biasm_kernel<<<(bmtot+255)/256, 256, 0, stream>>>(
        rpb + (size_t)blk*2535*NHEAD, bm, bmtot);
    // LN1 + roll + window gather: separate kernel only for block 0 (from x);
    // block 1's LN1 is fused into block 0's fc2-h1 epilogue.
    if (blk == 0)
      ln_kernel<<<NTOK/4, 256, 0, stream>>>(resid,
          ln1g, ln1b, buf1, 1, 0);
    // QKV GEMM -> packed attention tiles (q pre-scaled by 32^-0.5 * log2e)
    mm_kernel<128,0,0><<<dim3(392,3), 256, 0, stream>>>(
        buf1, wb, 128, qkvb + blk*384, bufq, 128,
        nullptr, nullptr, nullptr, nullptr, QKSCALE*LOG2E, 0, 0);
    // attention (128 windows x 4 heads), 8 waves/block
    attn_kernel<<<NWIN*NHEAD, 512, 0, stream>>>(bufq, bm, buf1, sh);
    // proj + reverse/roll-back scatter + residual -> outf; fused LN2 -> ln2o
    mm_kernel<128,2,1><<<dim3(392,1), 256, 0, stream>>>(
        buf1, wb+49152, 128, projb + blk*CC, ln2o, 0,
        outf, resid, ln2g + blk*CC, ln2b + blk*CC, 1.f, sh, 0);
    // MLP in 2 column-halves of 256 (hidden reuses bufq rows x 256)
    for (int h = 0; h < 2; ++h){
      mm_kernel<128,1,0><<<dim3(392,2), 256, 0, stream>>>(
          ln2o, wb + 65536 + (size_t)h*256*128, 128,
          fc1b + blk*512 + h*256, bufq, 256,
          nullptr, nullptr, nullptr, nullptr, 1.f, 0, 0);
      if (h == 0){
        mm_kernel<256,3,0><<<dim3(392,1), 256, 0, stream>>>(
            bufq, wb + 131072, 512,
            fc2b + blk*CC, nullptr, 0,
            outf, nullptr, nullptr, nullptr, 1.f, 0, 1);
      } else if (blk == 0){
        // final fc2 half of block 0: fuse LN1(+shifted window gather) for blk1
        mm_kernel<256,3,2><<<dim3(392,1), 256, 0, stream>>>(
            bufq, wb + 131072 + 256, 512,
            fc2b, buf1, 0,
            outf, nullptr, ln1g + CC, ln1b + CC, 1.f, 0, 0);
      } else {
        mm_kernel<256,3,0><<<dim3(392,1), 256, 0, stream>>>(
            bufq, wb + 131072 + 256, 512,
            fc2b + CC, nullptr, 0,
            outf, nullptr, nullptr, nullptr, 1.f, 0, 0);
      }
    }
  }
}

// Round 6
// 415.371 us; speedup vs baseline: 1.3467x; 1.1548x over previous
//
#include <hip/hip_runtime.h>
#include <hip/hip_bf16.h>
#include <math.h>

// VideoSwinBasicLayer: 2 swin blocks (W-MSA, SW-MSA) on (1,16,56,56,128), NH=4,
// window (8,7,7) -> L=392, nW=128, shift (4,3,3), HID=512. IO f32.
// R13: mm staging reverted to BK=32 m97 structure (R12's BK=128 single-stage
// reproduced the documented m132 occupancy regression). MLP un-split using the
// confirmed 256MiB workspace: fc1 one launch -> hid[NTOK][512], fc2 one KD=512
// launch (saves a full f32 residual RMW pass + 2 launches/blk). attn = R12
// (exp2-direct softmax, packed K/V tiles, linear global_load_lds staging).
// ws: buf1 12.85 | bufq 38.5 (ln2o overlaps V) | hid 51.4 | wts 0.79 | bm 10.44
//   = ~114 MB of the 256 MiB workspace.

#define NTOK 50176   // 16*56*56
#define CC   128
#define LL   392
#define NWIN 128
#define NHEAD 4
#define HDIM 32
#define QKSCALE 0.17677669529663687f  // 32^-0.5
#define LOG2E   1.4426950408889634f

// attention LDS layout (u16 units)
#define KOFF    0             // K: 392 rows x 32 (granule-swizzled) = 12544 u16
#define VOFF    12544         // V^T: 32 x 392 = 12544 u16
#define POFF    25088         // P: 8 waves x 1024 (16 q-rows x 128B, swizzled)
#define LDS_U16 33280         // 66560 B -> 2 blocks/CU

#define KTILE   12544         // u16 per (w,head) K or V tile

// K tile: row-major [row][32], b128 granule g (0..3) swizzled by row bits 0..3.
// Same formula on the global-write side (mm epilogue) and LDS-read side.
#define KADDR(row, g) (((row) << 5) + ((((g) ^ ((row) & 3) ^ (((row) >> 2) & 3))) << 3))
// V^T tile: [d][392] u16, linear. stride 392 u16 = 196 dw = 4 mod 32 -> 2-way max.
#define VADDR(d, k) (VOFF + (d)*392 + (k))

#define BM_PER_HEAD (13*392*16)            // u32 per (cls,head) slice
#define BM_TOTAL    (8*4*BM_PER_HEAD)      // 10.44 MB

typedef unsigned short u16;
typedef unsigned int   u32;
typedef unsigned long long u64;
typedef __attribute__((ext_vector_type(8))) short short8;
typedef __attribute__((ext_vector_type(4))) float f32x4;
typedef __attribute__((ext_vector_type(2))) unsigned int u32x2;
typedef __attribute__((ext_vector_type(4))) unsigned int u32x4;

// async global->LDS, 16B per lane; LDS dest = wave-uniform base + lane*16.
#define GLDS(gp, lp) __builtin_amdgcn_global_load_lds( \
    (const __attribute__((address_space(1))) void*)(gp), \
    (__attribute__((address_space(3))) void*)(lp), 16, 0, 0)

__device__ __forceinline__ float b2f_lo(u32 u){ return __uint_as_float(u<<16); }
__device__ __forceinline__ float b2f_hi(u32 u){ return __uint_as_float(u & 0xffff0000u); }
__device__ __forceinline__ u16 f2b(float f){
  __hip_bfloat16 h = __float2bfloat16(f);
  return *reinterpret_cast<u16*>(&h);
}
// pack 2 f32 -> 2 bf16 (RNE) in one instruction; lo->bits[15:0], hi->bits[31:16]
__device__ __forceinline__ u32 cvtpk(float lo, float hi){
  u32 r; asm("v_cvt_pk_bf16_f32 %0, %1, %2" : "=v"(r) : "v"(lo), "v"(hi)); return r;
}

// window-ordered row r -> flat token position (roll(+shift) both directions).
__device__ __forceinline__ int row_to_pos(int r, int shifted){
  int w = r / LL, t = r - w*LL;
  int wd = w >> 6, wh = (w >> 3) & 7, ww = w & 7;
  int td = t / 49, rem = t - td*49, th = rem / 7, tw = rem - th*7;
  int d = wd*8 + td, h = wh*7 + th, x = ww*7 + tw;
  if (shifted){ d = (d+4)&15; h += 3; if (h>=56) h-=56; x += 3; if (x>=56) x-=56; }
  return (d*56 + h)*56 + x;
}

// inverse of row_to_pos with shifted=1: flat token position -> window row.
__device__ __forceinline__ int pos_to_row_sh(int p){
  int d = p / 3136, rem = p - d*3136, h = rem / 56, x = rem - h*56;
  d = (d + 12) & 15; h -= 3; if (h < 0) h += 56; x -= 3; if (x < 0) x += 56;
  int wd = d >> 3, td = d & 7;
  int wh = h / 7, th = h - wh*7, ww = x / 7, tw = x - ww*7;
  return (wd*64 + wh*8 + ww)*LL + td*49 + th*7 + tw;
}

// LayerNorm over C=128 (f32 src), bf16 out. One wave per row.
__global__ __launch_bounds__(256) void ln_kernel(
    const float* __restrict__ xf, const float* __restrict__ g,
    const float* __restrict__ b, u16* __restrict__ out, int do_map, int shifted)
{
  int wave = threadIdx.x >> 6, lane = threadIdx.x & 63;
  int r = blockIdx.x*4 + wave;
  int pos = do_map ? row_to_pos(r, shifted) : r;
  long src = (long)pos * CC;
  float v0 = xf[src+lane], v1 = xf[src+64+lane];
  float s = v0+v1, ss = v0*v0 + v1*v1;
  #pragma unroll
  for (int o=32; o>0; o>>=1){ s += __shfl_xor(s,o); ss += __shfl_xor(ss,o); }
  float mean = s*(1.f/CC);
  float var  = ss*(1.f/CC) - mean*mean;
  float rstd = rsqrtf(var + 1e-5f);
  long dst = (long)r*CC;
  out[dst + lane]      = f2b((v0-mean)*rstd*g[lane]    + b[lane]);
  out[dst + 64 + lane] = f2b((v1-mean)*rstd*g[64+lane] + b[64+lane]);
}

// All 8 weight transposes (2 blocks x {qkv,proj,fc1,fc2}) in one launch.
__global__ __launch_bounds__(256) void wtall_kernel(
    const float* __restrict__ qkvw, const float* __restrict__ projw,
    const float* __restrict__ fc1w, const float* __restrict__ fc2w,
    u16* __restrict__ wts)
{
  int t = blockIdx.x*256 + threadIdx.x;               // 0..393215
  int blk = t / 196608, r = t - blk*196608;
  const float* in; int Kd, Nd, off;
  if (r < 49152)      { in = qkvw + (size_t)blk*49152; Kd = 128; Nd = 384; off = r; }
  else if (r < 65536) { in = projw + (size_t)blk*16384; Kd = 128; Nd = 128; off = r - 49152; }
  else if (r < 131072){ in = fc1w + (size_t)blk*65536;  Kd = 128; Nd = 512; off = r - 65536; }
  else                { in = fc2w + (size_t)blk*65536;  Kd = 512; Nd = 128; off = r - 131072; }
  int n = off / Kd, k = off - n*Kd;
  wts[t] = f2b(in[k*Nd + n]);
}

// Packed bias(+mask) table in exp2 domain, layout [cls][h][s][i][jj]:
// u32 = (bf16 v(j=s*32+jj, i), bf16 v(j+16, i)).
// v = (rpb-bias - 100*maskneq(cls)) * log2e;  j>=392 -> -1e30.
__global__ __launch_bounds__(256) void biasm_kernel(
    const float* __restrict__ rpb, u32* __restrict__ bm, int total)
{
  int t = blockIdx.x*256 + threadIdx.x;
  if (t >= total) return;
  int jj = t & 15; int rest = t >> 4;
  int i  = rest % 392; rest /= 392;
  int s  = rest % 13;  rest /= 13;
  int h  = rest & 3;   int cls = rest >> 2;
  int tdi=i/49, rmi=i-tdi*49, thi=rmi/7, twi=rmi-thi*7;
  u32 pack = 0;
  #pragma unroll
  for (int half=0; half<2; half++){
    int j = s*32 + jj + half*16;
    float v = -1e30f;
    if (j < LL){
      int tdj=j/49, rmj=j-tdj*49, thj=rmj/7, twj=rmj-thj*7;
      int idx = (tdi-tdj)*169 + (thi-thj)*13 + (twi-twj) + 1267;
      v = rpb[idx*NHEAD + h];
      bool neq = ((cls&4) && ((tdi<4) != (tdj<4)))
              || ((cls&2) && ((thi<4) != (thj<4)))
              || ((cls&1) && ((twi<4) != (twj<4)));
      if (neq) v -= 100.f;
      v *= LOG2E;
    }
    pack |= ((u32)f2b(v)) << (16*half);
  }
  bm[t] = pack;
}

// MFMA GEMM, m97-style BK=32 staging: C[128x128] = A[rows x KD](bf16) @ Wt^T.
// Unpadded LDS [128][32]; global_load_lds width 16 (4 issues/wave/K-iter).
// EPI: 0 = qkv packed epilogue (y0: Q*(scale)+b -> [row][128];
//          y1: K+b -> packed swizzled tiles; y2: V+b -> V^T tiles)
//      1 = +bias, GELU -> bf16 | 2 = +bias, scatter, +Res -> f32 | 3 = accum f32
// LNF: 0 = none | 1 = (EPI2) fuse LN -> OutB at scattered pos
//      2 = (EPI3) fuse LN -> OutB at shifted-window-gathered row
template<int KD, int EPI, int LNF>
__global__ __launch_bounds__(256) void mm_kernel(
    const u16* __restrict__ A, const u16* __restrict__ Wt, int ldw,
    const float* __restrict__ bias, u16* __restrict__ OutB, int ldo,
    float* __restrict__ OutF, const float* __restrict__ Res,
    const float* __restrict__ lng, const float* __restrict__ lnb,
    float scaleq, int shifted, int use_bias)
{
  __shared__ __align__(16) u16 As[128*32];
  __shared__ __align__(16) u16 Bs[128*32];
  const int tid = threadIdx.x, lane = tid & 63, wv = tid >> 6;
  const int quad = lane >> 4, l15 = lane & 15;
  const int rh = wv >> 1, ch = wv & 1;
  const int r0 = blockIdx.x * 128, n0 = blockIdx.y * 128;
  const int srow = lane >> 2, spart = (lane & 3) * 8;  // staging: 16 rows/issue

  f32x4 acc[4][4] = {};

  for (int kt = 0; kt < KD/32; kt++){
    const int k0 = kt*32;
    #pragma unroll
    for (int t=0;t<2;t++){
      const int rowbase = wv*32 + t*16;
      GLDS(&A [(long)(r0 + rowbase + srow)*KD  + k0 + spart], &As[rowbase*32]);
      GLDS(&Wt[(long)(n0 + rowbase + srow)*ldw + k0 + spart], &Bs[rowbase*32]);
    }
    __syncthreads();
    short8 af[4], bf[4];
    #pragma unroll
    for (int rt=0;rt<4;rt++)
      af[rt] = *reinterpret_cast<const short8*>(&As[(rh*64 + rt*16 + l15)*32 + quad*8]);
    #pragma unroll
    for (int ct=0;ct<4;ct++)
      bf[ct] = *reinterpret_cast<const short8*>(&Bs[(ch*64 + ct*16 + l15)*32 + quad*8]);
    #pragma unroll
    for (int rt=0;rt<4;rt++)
      #pragma unroll
      for (int ct=0;ct<4;ct++)
        acc[rt][ct] = __builtin_amdgcn_mfma_f32_16x16x32_bf16(af[rt], bf[ct], acc[rt][ct], 0,0,0);
    __syncthreads();
  }

  if (EPI == 0){
    const int y = blockIdx.y;
    if (y == 0){
      #pragma unroll
      for (int rt=0;rt<4;rt++)
        #pragma unroll
        for (int rr=0;rr<4;rr++){
          const int row_g = r0 + rh*64 + rt*16 + quad*4 + rr;
          #pragma unroll
          for (int ct=0;ct<4;ct++){
            const int c = ch*64 + ct*16 + l15;
            float v = (acc[rt][ct][rr] + bias[c]) * scaleq;
            OutB[(long)row_g*128 + c] = f2b(v);
          }
        }
    } else if (y == 1){
      u16* Kreg = OutB + (size_t)NTOK*128;
      #pragma unroll
      for (int rt=0;rt<4;rt++)
        #pragma unroll
        for (int rr=0;rr<4;rr++){
          const int row_g = r0 + rh*64 + rt*16 + quad*4 + rr;
          const int wi = row_g / 392, key = row_g - wi*392;
          #pragma unroll
          for (int ct=0;ct<4;ct++){
            const int c = ch*64 + ct*16 + l15;
            const int hd = c >> 5, d = c & 31;
            float v = acc[rt][ct][rr] + bias[128 + c];
            Kreg[(size_t)(wi*4 + hd)*KTILE + KADDR(key, d>>3) + (d&7)] = f2b(v);
          }
        }
    } else {
      u16* Vreg = OutB + (size_t)NTOK*256;
      #pragma unroll
      for (int rt=0;rt<4;rt++){
        const int rbase = r0 + rh*64 + rt*16 + quad*4;    // 4-aligned; 392%4==0
        const int wi = rbase / 392, key0 = rbase - wi*392; // -> never crosses w
        #pragma unroll
        for (int ct=0;ct<4;ct++){
          const int c = ch*64 + ct*16 + l15;
          const int hd = c >> 5, d = c & 31;
          const float bb = bias[256 + c];
          u32 lo = cvtpk(acc[rt][ct][0] + bb, acc[rt][ct][1] + bb);
          u32 hi = cvtpk(acc[rt][ct][2] + bb, acc[rt][ct][3] + bb);
          u64 pk = (u64)lo | ((u64)hi << 32);
          *reinterpret_cast<u64*>(&Vreg[(size_t)(wi*4 + hd)*KTILE + (size_t)d*392 + key0]) = pk;
        }
      }
    }
  } else if (LNF == 0){
    #pragma unroll
    for (int rt=0;rt<4;rt++){
      #pragma unroll
      for (int rr=0;rr<4;rr++){
        const int row_g = r0 + rh*64 + rt*16 + quad*4 + rr;
        long pos = 0;
        if (EPI == 2) pos = (long)row_to_pos(row_g, shifted) * CC;
        #pragma unroll
        for (int ct=0;ct<4;ct++){
          const int col_g = n0 + ch*64 + ct*16 + l15;
          float v = acc[rt][ct][rr];
          if (EPI == 1){
            v += bias[col_g];
            v = 0.5f*v*(1.f + erff(v*0.70710678118654752f));
            OutB[(long)row_g*ldo + col_g] = f2b(v);
          } else if (EPI == 2){
            OutF[pos + col_g] = Res[pos + col_g] + v + bias[col_g];
          } else {
            float o = OutF[(long)row_g*CC + col_g] + v;
            if (use_bias) o += bias[col_g];
            OutF[(long)row_g*CC + col_g] = o;
          }
        }
      }
    }
  } else {
    // fused LayerNorm epilogue (requires full 128-col rows: gridDim.y == 1).
    float* red = (float*)As;     // [128 rows][2 ch][2 stats] = 2KB, reuse As
    int pose[4][4];
    #pragma unroll
    for (int rt=0;rt<4;rt++){
      #pragma unroll
      for (int rr=0;rr<4;rr++){
        const int row_g = r0 + rh*64 + rt*16 + quad*4 + rr;
        int pos = (EPI == 2) ? row_to_pos(row_g, shifted) : row_g;
        pose[rt][rr] = pos;
        long pb = (long)pos * CC;
        float s = 0.f, ss = 0.f;
        #pragma unroll
        for (int ct=0;ct<4;ct++){
          const int col_g = n0 + ch*64 + ct*16 + l15;
          float v = acc[rt][ct][rr];
          float o;
          if (EPI == 2) o = Res[pb + col_g] + v + bias[col_g];
          else { o = OutF[pb + col_g] + v; if (use_bias) o += bias[col_g]; }
          OutF[pb + col_g] = o;
          acc[rt][ct][rr] = o;
          s += o; ss += o*o;
        }
        #pragma unroll
        for (int off=1; off<16; off<<=1){
          s  += __shfl_xor(s,  off);
          ss += __shfl_xor(ss, off);
        }
        if (l15 == 0){
          int rl = rh*64 + rt*16 + quad*4 + rr;
          red[rl*4 + ch*2]     = s;
          red[rl*4 + ch*2 + 1] = ss;
        }
      }
    }
    __syncthreads();
    #pragma unroll
    for (int rt=0;rt<4;rt++){
      #pragma unroll
      for (int rr=0;rr<4;rr++){
        const int rl = rh*64 + rt*16 + quad*4 + rr;
        float st  = red[rl*4]     + red[rl*4 + 2];
        float sst = red[rl*4 + 1] + red[rl*4 + 3];
        float mean = st*(1.f/128.f);
        float var  = sst*(1.f/128.f) - mean*mean;
        float rstd = rsqrtf(var + 1e-5f);
        long oidx;
        if (LNF == 1) oidx = (long)pose[rt][rr] * CC;            // linear-pos out
        else          oidx = (long)pos_to_row_sh(pose[rt][rr]) * CC; // window out
        #pragma unroll
        for (int ct=0;ct<4;ct++){
          const int col_g = n0 + ch*64 + ct*16 + l15;
          float val = (acc[rt][ct][rr] - mean)*rstd*lng[col_g] + lnb[col_g];
          OutB[oidx + col_g] = f2b(val);
        }
      }
    }
  }
}

// MFMA flash attention, S^T orientation. One block per (window, head); 8 waves
// x 16-row q-tiles (qt += 8). K/V^T staged via linear global_load_lds from the
// packed tiles the qkv GEMM emitted. exp2-DIRECT softmax: no max tracking
// (logits structurally bounded; mask bias -144 -> exp2 -> exact 0). Per-lane
// partial denominator, reduced once per q-tile.
__global__ __launch_bounds__(512, 4) void attn_kernel(
    const u16* __restrict__ qkv, const u32* __restrict__ bm,
    u16* __restrict__ out, int shifted)
{
  __shared__ __align__(16) u16 lds[LDS_U16];

  const int w = blockIdx.x >> 2, head = blockIdx.x & 3;
  const int tid = threadIdx.x, lane = tid & 63, wave = tid >> 6;
  const int quad = lane >> 4, l15 = lane & 15;
  const int wd = w>>6, wh = (w>>3)&7, ww = w&7;
  const int cls = shifted ? (((wd!=0)?4:0) | ((wh==7)?2:0) | ((ww==7)?1:0)) : 0;
  const u32* __restrict__ bmh = bm + (size_t)(cls*NHEAD + head)*BM_PER_HEAD;
  const int pbase = POFF + wave*1024;
  const int swz = l15 & 7;
  const int prow = pbase + l15*64;
  const int q2 = quad >> 1, qh = (quad & 1) << 2;

  // stage K tile (25088B) and V^T tile (25088B), both linear
  {
    const u16* Kg = qkv + (size_t)NTOK*128 + (size_t)(w*4+head)*KTILE;
    const u16* Vg = qkv + (size_t)NTOK*256 + (size_t)(w*4+head)*KTILE;
    #pragma unroll
    for (int n = 0; n < 3; n++){
      GLDS(Kg + n*4096 + wave*512 + (lane<<3), &lds[KOFF + n*4096 + wave*512]);
      GLDS(Vg + n*4096 + wave*512 + (lane<<3), &lds[VOFF + n*4096 + wave*512]);
    }
    if (tid < 32){
      GLDS(Kg + 12288 + (lane<<3), &lds[KOFF + 12288]);
      GLDS(Vg + 12288 + (lane<<3), &lds[VOFF + 12288]);
    }
  }
  __syncthreads();

  for (int qt = wave; qt < 25; qt += 8){
    int iq = qt*16 + l15; if (iq > LL-1) iq = LL-1;
    short8 qf = *reinterpret_cast<const short8*>(
        &qkv[((size_t)(w*LL + iq))*128 + head*HDIM + quad*8]);

    float ls = 0.f;
    f32x4 oc0 = {0.f,0.f,0.f,0.f}, oc1 = {0.f,0.f,0.f,0.f};

    const int bmrow = iq*16 + quad*4;
    u32x4 bmA = *reinterpret_cast<const u32x4*>(&bmh[bmrow]);            // s=0
    u32x4 bmB = *reinterpret_cast<const u32x4*>(&bmh[392*16 + bmrow]);   // s=1
    short8 kf0 = *reinterpret_cast<const short8*>(&lds[KOFF + KADDR(     l15, quad)]);
    short8 kf1 = *reinterpret_cast<const short8*>(&lds[KOFF + KADDR(16 + l15, quad)]);
    short8 kf2 = *reinterpret_cast<const short8*>(&lds[KOFF + KADDR(32 + l15, quad)]);
    short8 kf3 = *reinterpret_cast<const short8*>(&lds[KOFF + KADDR(48 + l15, quad)]);

    for (int it = 0; it < 6; it++){
      const int kb = it*64;
      // prefetch next 64-key group (or the clamped 32-key tail when it==5)
      u32x4 bmAn = {}, bmBn = {};
      short8 kn0 = {}, kn1 = {}, kn2 = {}, kn3 = {};
      if (it < 5){
        bmAn = *reinterpret_cast<const u32x4*>(&bmh[(2*it+2)*392*16 + bmrow]);
        bmBn = *reinterpret_cast<const u32x4*>(&bmh[(2*it+3)*392*16 + bmrow]);
        kn0 = *reinterpret_cast<const short8*>(&lds[KOFF + KADDR(kb + 64 + l15, quad)]);
        kn1 = *reinterpret_cast<const short8*>(&lds[KOFF + KADDR(kb + 80 + l15, quad)]);
        kn2 = *reinterpret_cast<const short8*>(&lds[KOFF + KADDR(kb + 96 + l15, quad)]);
        kn3 = *reinterpret_cast<const short8*>(&lds[KOFF + KADDR(kb +112 + l15, quad)]);
      } else {
        bmAn = *reinterpret_cast<const u32x4*>(&bmh[12*392*16 + bmrow]);
        // tail K rows clamped to real rows 384..391; bias -1e30 kills keys>=392
        kn0 = *reinterpret_cast<const short8*>(&lds[KOFF + KADDR(384 + (l15 & 7), quad)]);
        kn1 = kn0;
      }

      f32x4 z = {0.f,0.f,0.f,0.f};
      __builtin_amdgcn_s_setprio(1);
      f32x4 c0 = __builtin_amdgcn_mfma_f32_16x16x32_bf16(kf0, qf, z, 0,0,0);
      f32x4 c1 = __builtin_amdgcn_mfma_f32_16x16x32_bf16(kf1, qf, z, 0,0,0);
      f32x4 c2 = __builtin_amdgcn_mfma_f32_16x16x32_bf16(kf2, qf, z, 0,0,0);
      f32x4 c3 = __builtin_amdgcn_mfma_f32_16x16x32_bf16(kf3, qf, z, 0,0,0);
      __builtin_amdgcn_s_setprio(0);
      // c0[r]: S[key=kb+quad*4+r][q=iq]; c1: +16; c2: +32; c3: +48 (log2 dom.)

      float p0[4], p1[4], p2[4], p3[4];
      #pragma unroll
      for (int r=0;r<4;r++){
        p0[r] = exp2f(c0[r] + b2f_lo(bmA[r]));
        p1[r] = exp2f(c1[r] + b2f_hi(bmA[r]));
        p2[r] = exp2f(c2[r] + b2f_lo(bmB[r]));
        p3[r] = exp2f(c3[r] + b2f_hi(bmB[r]));
        ls += (p0[r] + p1[r]) + (p2[r] + p3[r]);
      }

      // P -> wave-private LDS (16 rows x 8 granules, granule ^= l15&7)
      u32x2 w0, w1, w2, w3;
      w0.x = cvtpk(p0[0], p0[1]); w0.y = cvtpk(p0[2], p0[3]);
      w1.x = cvtpk(p1[0], p1[1]); w1.y = cvtpk(p1[2], p1[3]);
      w2.x = cvtpk(p2[0], p2[1]); w2.y = cvtpk(p2[2], p2[3]);
      w3.x = cvtpk(p3[0], p3[1]); w3.y = cvtpk(p3[2], p3[3]);
      *reinterpret_cast<u32x2*>(&lds[prow + (((0 + q2) ^ swz) << 3) + qh]) = w0;
      *reinterpret_cast<u32x2*>(&lds[prow + (((2 + q2) ^ swz) << 3) + qh]) = w1;
      *reinterpret_cast<u32x2*>(&lds[prow + (((4 + q2) ^ swz) << 3) + qh]) = w2;
      *reinterpret_cast<u32x2*>(&lds[prow + (((6 + q2) ^ swz) << 3) + qh]) = w3;

      short8 pa0 = *reinterpret_cast<const short8*>(&lds[prow + (((quad    ) ^ swz) << 3)]);
      short8 pa1 = *reinterpret_cast<const short8*>(&lds[prow + (((quad + 4) ^ swz) << 3)]);
      short8 vb00 = *reinterpret_cast<const short8*>(&lds[VADDR(     l15, kb      + quad*8)]);
      short8 vb01 = *reinterpret_cast<const short8*>(&lds[VADDR(16 + l15, kb      + quad*8)]);
      short8 vb10 = *reinterpret_cast<const short8*>(&lds[VADDR(     l15, kb + 32 + quad*8)]);
      short8 vb11 = *reinterpret_cast<const short8*>(&lds[VADDR(16 + l15, kb + 32 + quad*8)]);
      __builtin_amdgcn_s_setprio(1);
      oc0 = __builtin_amdgcn_mfma_f32_16x16x32_bf16(pa0, vb00, oc0, 0,0,0);
      oc1 = __builtin_amdgcn_mfma_f32_16x16x32_bf16(pa0, vb01, oc1, 0,0,0);
      oc0 = __builtin_amdgcn_mfma_f32_16x16x32_bf16(pa1, vb10, oc0, 0,0,0);
      oc1 = __builtin_amdgcn_mfma_f32_16x16x32_bf16(pa1, vb11, oc1, 0,0,0);
      __builtin_amdgcn_s_setprio(0);

      bmA = bmAn; bmB = bmBn;
      kf0 = kn0; kf1 = kn1; kf2 = kn2; kf3 = kn3;
    }

    // tail: keys 384..415 (K rows clamped; bias kills keys >= 392)
    {
      f32x4 z = {0.f,0.f,0.f,0.f};
      f32x4 c0 = __builtin_amdgcn_mfma_f32_16x16x32_bf16(kf0, qf, z, 0,0,0);
      f32x4 c1 = __builtin_amdgcn_mfma_f32_16x16x32_bf16(kf1, qf, z, 0,0,0);
      float p0[4], p1[4];
      #pragma unroll
      for (int r=0;r<4;r++){
        p0[r] = exp2f(c0[r] + b2f_lo(bmA[r]));
        p1[r] = exp2f(c1[r] + b2f_hi(bmA[r]));
        ls += p0[r] + p1[r];
      }
      u32x2 w0, w1;
      w0.x = cvtpk(p0[0], p0[1]); w0.y = cvtpk(p0[2], p0[3]);
      w1.x = cvtpk(p1[0], p1[1]); w1.y = cvtpk(p1[2], p1[3]);
      *reinterpret_cast<u32x2*>(&lds[prow + (((0 + q2) ^ swz) << 3) + qh]) = w0;
      *reinterpret_cast<u32x2*>(&lds[prow + (((2 + q2) ^ swz) << 3) + qh]) = w1;
      short8 pa0 = *reinterpret_cast<const short8*>(&lds[prow + ((quad ^ swz) << 3)]);
      // V clamped to keys 384..391 for all k-slots; P==0 for keys >= 392
      short8 vb0 = *reinterpret_cast<const short8*>(&lds[VADDR(     l15, 384)]);
      short8 vb1 = *reinterpret_cast<const short8*>(&lds[VADDR(16 + l15, 384)]);
      oc0 = __builtin_amdgcn_mfma_f32_16x16x32_bf16(pa0, vb0, oc0, 0,0,0);
      oc1 = __builtin_amdgcn_mfma_f32_16x16x32_bf16(pa0, vb1, oc1, 0,0,0);
    }

    // denominator: reduce per-lane partials once per q-tile
    ls += __shfl_xor(ls, 16);
    ls += __shfl_xor(ls, 32);
    float inv = 1.f / ls;
    #pragma unroll
    for (int r=0;r<4;r++){
      float invr = __shfl(inv, quad*4 + r);
      int i = qt*16 + quad*4 + r;
      if (i < LL){
        long o = ((long)(w*LL + i))*CC + head*HDIM;
        out[o + l15]      = f2b(oc0[r]*invr);
        out[o + 16 + l15] = f2b(oc1[r]*invr);
      }
    }
  }
}

extern "C" void kernel_launch(void* const* d_in, const int* in_sizes, int n_in,
                              void* d_out, int out_size, void* d_ws, size_t ws_size,
                              hipStream_t stream)
{
  const float* x     = (const float*)d_in[0];
  const float* ln1g  = (const float*)d_in[1];
  const float* ln1b  = (const float*)d_in[2];
  const float* qkvw  = (const float*)d_in[3];
  const float* qkvb  = (const float*)d_in[4];
  const float* rpb   = (const float*)d_in[5];
  const float* projw = (const float*)d_in[6];
  const float* projb = (const float*)d_in[7];
  const float* ln2g  = (const float*)d_in[8];
  const float* ln2b  = (const float*)d_in[9];
  const float* fc1w  = (const float*)d_in[10];
  const float* fc1b  = (const float*)d_in[11];
  const float* fc2w  = (const float*)d_in[12];
  const float* fc2b  = (const float*)d_in[13];
  float* outf = (float*)d_out;                  // f32 residual stream / output

  u16* buf1 = (u16*)d_ws;                       // bf16 act (window space), NTOK*128
  u16* bufq = buf1 + (size_t)NTOK*CC;           // Q | Kpack | V^T  (NTOK*384 u16)
  u16* ln2o = bufq + (size_t)NTOK*256;          // LN2 out (overlays V^T, dead then)
  u16* hid  = bufq + (size_t)NTOK*384;          // MLP hidden, NTOK*512 u16
  u16* wts  = hid  + (size_t)NTOK*512;          // transposed bf16 weights
  u32* bm   = (u32*)(wts + 393216);             // packed bias+mask table

  // all weight transposes in one launch
  wtall_kernel<<<1536, 256, 0, stream>>>(qkvw, projw, fc1w, fc2w, wts);

  for (int blk = 0; blk < 2; ++blk){
    const int sh = blk;
    const float* resid = (blk==0) ? x : outf;
    u16* wb = wts + (size_t)blk*196608;

    // block 0 (unshifted) only uses mask class 0 -> build 1/8 of the table
    const int bmtot = (blk==0) ? 4*BM_PER_HEAD : BM_TOTAL;
    biasm_kernel<<<(bmtot+255)/256, 256, 0, stream>>>(
        rpb + (size_t)blk*2535*NHEAD, bm, bmtot);
    // LN1 + roll + window gather: separate kernel only for block 0 (from x);
    // block 1's LN1 is fused into block 0's fc2 epilogue.
    if (blk == 0)
      ln_kernel<<<NTOK/4, 256, 0, stream>>>(resid,
          ln1g, ln1b, buf1, 1, 0);
    // QKV GEMM -> packed attention tiles (q pre-scaled by 32^-0.5 * log2e)
    mm_kernel<128,0,0><<<dim3(392,3), 256, 0, stream>>>(
        buf1, wb, 128, qkvb + blk*384, bufq, 128,
        nullptr, nullptr, nullptr, nullptr, QKSCALE*LOG2E, 0, 0);
    // attention (128 windows x 4 heads), 8 waves/block
    attn_kernel<<<NWIN*NHEAD, 512, 0, stream>>>(bufq, bm, buf1, sh);
    // proj + reverse/roll-back scatter + residual -> outf; fused LN2 -> ln2o
    mm_kernel<128,2,1><<<dim3(392,1), 256, 0, stream>>>(
        buf1, wb+49152, 128, projb + blk*CC, ln2o, 0,
        outf, resid, ln2g + blk*CC, ln2b + blk*CC, 1.f, sh, 0);
    // MLP: fc1 one launch (4 column-blocks) -> hid[NTOK][512]
    mm_kernel<128,1,0><<<dim3(392,4), 256, 0, stream>>>(
        ln2o, wb + 65536, 128,
        fc1b + blk*512, hid, 512,
        nullptr, nullptr, nullptr, nullptr, 1.f, 0, 0);
    // fc2 one launch, KD=512, +bias, +residual(outf in place)
    if (blk == 0){
      // fuse LN1(+shifted window gather) for block 1 -> buf1
      mm_kernel<512,3,2><<<dim3(392,1), 256, 0, stream>>>(
          hid, wb + 131072, 512,
          fc2b, buf1, 0,
          outf, nullptr, ln1g + CC, ln1b + CC, 1.f, 0, 1);
    } else {
      mm_kernel<512,3,0><<<dim3(392,1), 256, 0, stream>>>(
          hid, wb + 131072, 512,
          fc2b + CC, nullptr, 0,
          outf, nullptr, nullptr, nullptr, 1.f, 0, 1);
    }
  }
}